// Round 4
// baseline (5835.076 us; speedup 1.0000x reference)
//
#include <hip/hip_runtime.h>
#include <stdint.h>

#define H_NODES 8191
#define NN 4096
#define DIMC 1024
#define NBLK 256

typedef __bf16 bf16x8 __attribute__((ext_vector_type(8)));
typedef float f32x4 __attribute__((ext_vector_type(4)));

__device__ __forceinline__ float b2f(ushort u) {
  union { uint32_t i; float f; } x; x.i = ((uint32_t)u) << 16; return x.f;
}
__device__ __forceinline__ ushort f2b(float f) {
  union { float f; uint32_t i; } x; x.f = f;
  uint32_t r = x.i + 0x7FFFu + ((x.i >> 16) & 1u);
  return (ushort)(r >> 16);
}
__device__ __forceinline__ void load16f(const ushort* p, float* f) {
  const uint32_t* w = (const uint32_t*)p;
  #pragma unroll
  for (int i = 0; i < 8; ++i) {
    uint32_t v = w[i];
    f[2 * i]     = b2f((ushort)(v & 0xffff));
    f[2 * i + 1] = b2f((ushort)(v >> 16));
  }
}
__device__ __forceinline__ void store16b(ushort* p, const float* f) {
  uint32_t w[8];
  #pragma unroll
  for (int i = 0; i < 8; ++i)
    w[i] = (uint32_t)f2b(f[2 * i]) | ((uint32_t)f2b(f[2 * i + 1]) << 16);
  *(uint4*)p = *(const uint4*)&w[0];
  *(uint4*)(p + 8) = *(const uint4*)&w[4];
}

// ---------------- weight transpose + fp32->bf16
struct WPtrs { const float* w[8]; };

__global__ void __launch_bounds__(256) transpose_w_k(WPtrs wp, ushort* __restrict__ dst) {
  __shared__ float t[32][33];
  const float* src = wp.w[blockIdx.z];
  int c0 = blockIdx.x * 32, r0 = blockIdx.y * 32;
  int tx = threadIdx.x, ty = threadIdx.y;
  #pragma unroll
  for (int i = ty; i < 32; i += 8)
    t[i][tx] = src[(long)(r0 + i) * DIMC + c0 + tx];
  __syncthreads();
  ushort* d = dst + (long)blockIdx.z * DIMC * DIMC;
  #pragma unroll
  for (int i = ty; i < 32; i += 8)
    d[(long)(c0 + i) * DIMC + r0 + tx] = f2b(t[tx][i]);
}

// ---------------- x fp32 -> h leaf rows (bf16); block 0 thread 0 zeroes the grid barrier
__global__ void __launch_bounds__(256) cvt_x_k(const float* __restrict__ x,
    ushort* __restrict__ h, int* __restrict__ bar) {
  if (blockIdx.x == 0 && threadIdx.x == 0) { bar[0] = 0; bar[1] = 0; }
  long t = (long)blockIdx.x * 256 + threadIdx.x;
  long i = t << 2;
  if (i >= (long)2 * NN * DIMC) return;
  long row = i >> 10;
  int col = (int)(i & 1023);
  long b = row >> 12;
  long n = row & 4095;
  float4 v = *(const float4*)(x + i);
  ushort* d = h + ((b * H_NODES + n) << 10) + col;
  uint2 pk;
  pk.x = (uint32_t)f2b(v.x) | ((uint32_t)f2b(v.y) << 16);
  pk.y = (uint32_t)f2b(v.z) | ((uint32_t)f2b(v.w) << 16);
  *(uint2*)d = pk;
}

// ---------------- grid-wide barrier (256 co-resident blocks)
__device__ __forceinline__ void grid_bar(int* bar, int& gen) {
  __syncthreads();
  if (threadIdx.x == 0) {
    int slot = gen & 1;
    __threadfence();
    int prev = __hip_atomic_fetch_add(&bar[slot], 1, __ATOMIC_ACQ_REL, __HIP_MEMORY_SCOPE_AGENT);
    if (prev == NBLK - 1)
      __hip_atomic_store(&bar[slot ^ 1], 0, __ATOMIC_RELAXED, __HIP_MEMORY_SCOPE_AGENT);
    while (__hip_atomic_load(&bar[slot], __ATOMIC_ACQUIRE, __HIP_MEMORY_SCOPE_AGENT) < NBLK)
      __builtin_amdgcn_s_sleep(2);
    __threadfence();
  }
  __syncthreads();
  ++gen;
}

// ---------------- shared MFMA inner step (reads swizzled LDS frags, 16 MFMA)
__device__ __forceinline__ void mfma_step(const ushort* a, const ushort* b,
    f32x4 (&acc)[4][4], int wr, int wc, int rr, int g4) {
  bf16x8 af[4], bfr[4];
  #pragma unroll
  for (int m = 0; m < 4; ++m) {
    int r = wr * 64 + m * 16 + rr;
    int slot = g4 ^ ((r >> 1) & 3);
    af[m] = *reinterpret_cast<const bf16x8*>(a + r * 32 + slot * 8);
  }
  #pragma unroll
  for (int n = 0; n < 4; ++n) {
    int r = wc * 64 + n * 16 + rr;
    int slot = g4 ^ ((r >> 1) & 3);
    bfr[n] = *reinterpret_cast<const bf16x8*>(b + r * 32 + slot * 8);
  }
  __builtin_amdgcn_s_setprio(1);
  #pragma unroll
  for (int m = 0; m < 4; ++m)
    #pragma unroll
    for (int n = 0; n < 4; ++n)
      acc[m][n] = __builtin_amdgcn_mfma_f32_16x16x32_bf16(af[m], bfr[n], acc[m][n], 0, 0, 0);
  __builtin_amdgcn_s_setprio(0);
}

__device__ __forceinline__ void cwrite(f32x4 (&acc)[4][4], const float* bias,
    void* Cp, int ldc, int M, int outMode, int row0, int col0, int wr, int wc, int lane) {
  int rr = lane & 15, rq = lane >> 4;
  #pragma unroll
  for (int n = 0; n < 4; ++n) {
    int col = col0 + wc * 64 + n * 16 + rr;
    float bv = bias ? bias[col] : 0.0f;
    #pragma unroll
    for (int m = 0; m < 4; ++m) {
      int gr0 = row0 + wr * 64 + m * 16 + rq * 4;
      #pragma unroll
      for (int r = 0; r < 4; ++r) {
        int gr = gr0 + r;
        if (gr < M) {
          float vv = acc[m][n][r] + bv;
          long o = (long)gr * ldc + col;
          if (outMode == 2) ((float*)Cp)[o] = vv;
          else ((ushort*)Cp)[o] = f2b(vv);
        }
      }
    }
  }
}

// ---------------- 128x128 pipelined GEMM tile, gload_lds staging (3-buf)
__device__ void gemm_tile_g(const ushort* __restrict__ A, int M,
    const ushort* __restrict__ Bt, const float* bias, void* Cp, int ldc, int outMode,
    int row0, int col0, ushort (*lA)[4096], ushort (*lB)[4096]) {
  __syncthreads();   // protect LDS reuse across sequential tiles
  int tid = threadIdx.x, wave = tid >> 6, lane = tid & 63;
  int wr = wave >> 1, wc = wave & 1;
  f32x4 acc[4][4];
  #pragma unroll
  for (int m = 0; m < 4; ++m)
    #pragma unroll
    for (int n = 0; n < 4; ++n) acc[m][n] = (f32x4){0.f, 0.f, 0.f, 0.f};

  auto stage = [&](int kt, int buf) {
    #pragma unroll
    for (int j = 0; j < 2; ++j) {
      int s = wave * 128 + j * 64 + lane;
      int r = s >> 2;
      int g = (s & 3) ^ ((r >> 1) & 3);
      int gr = row0 + r; gr = (gr < M) ? gr : (M - 1);
      __builtin_amdgcn_global_load_lds(
          (const __attribute__((address_space(1))) void*)(uintptr_t)(A + (long)gr * DIMC + kt * 32 + g * 8),
          (__attribute__((address_space(3))) void*)(uint32_t)(uintptr_t)(lA[buf] + s * 8), 16, 0, 0);
      __builtin_amdgcn_global_load_lds(
          (const __attribute__((address_space(1))) void*)(uintptr_t)(Bt + (long)(col0 + r) * DIMC + kt * 32 + g * 8),
          (__attribute__((address_space(3))) void*)(uint32_t)(uintptr_t)(lB[buf] + s * 8), 16, 0, 0);
    }
  };
  stage(0, 0); stage(1, 1);
  asm volatile("s_waitcnt vmcnt(4)" ::: "memory");
  __builtin_amdgcn_s_barrier();

  int rr = lane & 15, g4 = lane >> 4;
  for (int kt = 0; kt < 32; ++kt) {
    int cur = kt % 3;
    if (kt + 2 < 32) stage(kt + 2, (kt + 2) % 3);
    mfma_step(lA[cur], lB[cur], acc, wr, wc, rr, g4);
    if (kt < 30) { asm volatile("s_waitcnt vmcnt(4)" ::: "memory"); }
    else         { asm volatile("s_waitcnt vmcnt(0)" ::: "memory"); }
    if (kt < 31) __builtin_amdgcn_s_barrier();
  }
  cwrite(acc, bias, Cp, ldc, M, outMode, row0, col0, wr, wc, lane);
}

// ---------------- 128x128 GEMM tile with A = 0.5*(child0+child1), reg-staged (2-buf)
__device__ void gemm_tile_avg(const ushort* __restrict__ Hc, int M,
    const ushort* __restrict__ Bt, ushort* Cp, int ldc,
    int row0, int col0, ushort (*lA)[4096], ushort (*lB)[4096]) {
  __syncthreads();
  int tid = threadIdx.x, wave = tid >> 6, lane = tid & 63;
  int wr = wave >> 1, wc = wave & 1;
  f32x4 acc[4][4];
  #pragma unroll
  for (int m = 0; m < 4; ++m)
    #pragma unroll
    for (int n = 0; n < 4; ++n) acc[m][n] = (f32x4){0.f, 0.f, 0.f, 0.f};

  uint4 ra0[2], ra1[2], rb[2];
  auto loadS = [&](int kt) {
    #pragma unroll
    for (int j = 0; j < 2; ++j) {
      int s = wave * 128 + j * 64 + lane;
      int r = s >> 2;
      int g = (s & 3) ^ ((r >> 1) & 3);
      int pr = row0 + r; pr = (pr < M) ? pr : (M - 1);
      const ushort* c0 = Hc + ((long)(2 * pr) << 10) + kt * 32 + g * 8;
      ra0[j] = *(const uint4*)c0;
      ra1[j] = *(const uint4*)(c0 + DIMC);
      rb[j] = *(const uint4*)(Bt + (long)(col0 + r) * DIMC + kt * 32 + g * 8);
    }
  };
  auto writeS = [&](int buf) {
    #pragma unroll
    for (int j = 0; j < 2; ++j) {
      int s = wave * 128 + j * 64 + lane;
      uint32_t ow[4];
      const uint32_t* pa = (const uint32_t*)&ra0[j];
      const uint32_t* pb = (const uint32_t*)&ra1[j];
      #pragma unroll
      for (int i = 0; i < 4; ++i) {
        float x0 = b2f((ushort)(pa[i] & 0xffff)), x1 = b2f((ushort)(pa[i] >> 16));
        float y0 = b2f((ushort)(pb[i] & 0xffff)), y1 = b2f((ushort)(pb[i] >> 16));
        ow[i] = (uint32_t)f2b(0.5f * (x0 + y0)) | ((uint32_t)f2b(0.5f * (x1 + y1)) << 16);
      }
      *(uint4*)(lA[buf] + s * 8) = *(const uint4*)ow;
      *(uint4*)(lB[buf] + s * 8) = rb[j];
    }
  };
  loadS(0); writeS(0); loadS(1);
  asm volatile("s_waitcnt lgkmcnt(0)" ::: "memory");
  __builtin_amdgcn_s_barrier();

  int rr = lane & 15, g4 = lane >> 4;
  for (int kt = 0; kt < 32; ++kt) {
    if (kt + 1 < 32) writeS((kt + 1) & 1);   // regs of loadS(kt+1)
    if (kt + 2 < 32) loadS(kt + 2);
    mfma_step(lA[kt & 1], lB[kt & 1], acc, wr, wc, rr, g4);
    asm volatile("s_waitcnt lgkmcnt(0)" ::: "memory");
    if (kt < 31) __builtin_amdgcn_s_barrier();
  }
  cwrite(acc, nullptr, Cp, ldc, M, 0, row0, col0, wr, wc, lane);
}

// ---------------- stage-1 2-child merge: one wave per (b,p)
__device__ __forceinline__ void merge_one(const ushort* __restrict__ q,
    const ushort* __restrict__ kv, ushort* __restrict__ outp, int P, int w, int lane) {
  int b = (w >= P) ? 1 : 0;
  int p = w - b * P;
  const ushort* qp = q + (((long)(b * P + p)) << 10) + lane * 16;
  const ushort* kvb = kv + ((long)(b * 2 * P + 2 * p)) * 2048;
  float qf[16], k0f[16], k1f[16];
  load16f(qp, qf);
  load16f(kvb + lane * 16, k0f);
  load16f(kvb + 2048 + lane * 16, k1f);
  float d0 = 0.f, d1 = 0.f;
  #pragma unroll
  for (int j = 0; j < 16; ++j) { d0 += qf[j] * k0f[j]; d1 += qf[j] * k1f[j]; }
  d0 += __shfl_xor(d0, 1); d0 += __shfl_xor(d0, 2);
  d1 += __shfl_xor(d1, 1); d1 += __shfl_xor(d1, 2);
  float s0 = d0 * 0.125f, s1 = d1 * 0.125f;
  float mm = fmaxf(s0, s1);
  float e0 = expf(s0 - mm), e1 = expf(s1 - mm);
  float inv = 1.0f / (e0 + e1 + 1e-9f);
  float w0 = e0 * inv, w1 = e1 * inv;
  float v0f[16], v1f[16], ov[16];
  load16f(kvb + 1024 + lane * 16, v0f);
  load16f(kvb + 2048 + 1024 + lane * 16, v1f);
  #pragma unroll
  for (int j = 0; j < 16; ++j) ov[j] = w0 * v0f[j] + w1 * v1f[j];
  store16b(outp + (((long)(b * P + p)) << 10) + lane * 16, ov);
}

// ---------------- stage-2 gather attention: one wave per (b,n)
__device__ __forceinline__ void attn_one(const ushort* __restrict__ Q,
    const ushort* __restrict__ KV, ushort* __restrict__ outp, int w, int lane) {
  int n = w & 4095;
  int b = w >> 12;
  const ushort* KVb = KV + (long)b * H_NODES * 2048;
  float qf[16];
  load16f(Q + (((long)b * NN + n) << 10) + lane * 16, qf);
  int nb[13];
  nb[0] = n;
  #pragma unroll
  for (int l = 0; l < 12; ++l) nb[1 + l] = (8192 - (8192 >> l)) + ((n >> l) ^ 1);
  float s[13];
  #pragma unroll
  for (int i = 0; i < 13; ++i) {
    float kf[16];
    load16f(KVb + (long)nb[i] * 2048 + lane * 16, kf);
    float d = 0.f;
    #pragma unroll
    for (int j = 0; j < 16; ++j) d += qf[j] * kf[j];
    d += __shfl_xor(d, 1);
    d += __shfl_xor(d, 2);
    s[i] = d * 0.125f;
  }
  #pragma unroll
  for (int l = 0; l < 12; ++l)
    if (((n >> l) & 1) == 0) s[1 + l] = -__builtin_inff();
  float mm = s[0];
  #pragma unroll
  for (int i = 1; i < 13; ++i) mm = fmaxf(mm, s[i]);
  float e[13], sum = 0.f;
  #pragma unroll
  for (int i = 0; i < 13; ++i) { e[i] = expf(s[i] - mm); sum += e[i]; }
  float inv = 1.0f / sum;
  float ov[16];
  #pragma unroll
  for (int j = 0; j < 16; ++j) ov[j] = 0.f;
  #pragma unroll
  for (int i = 0; i < 13; ++i) {
    float wgt = e[i] * inv;
    float vf[16];
    load16f(KVb + (long)nb[i] * 2048 + 1024 + lane * 16, vf);
    #pragma unroll
    for (int j = 0; j < 16; ++j) ov[j] += wgt * vf[j];
  }
  store16b(outp + (((long)b * NN + n) << 10) + lane * 16, ov);
}

// ---------------- the persistent kernel: all 12 levels + stage 2
struct PersArgs {
  ushort* h; const ushort* wt; const float* boy; const float* box;
  ushort* qb; ushort* kv1; ushort* mrg;
  ushort* Qx; ushort* KVa; ushort* aout; float* outp;
  int* bar;
};

__global__ void __launch_bounds__(256) tree_pers_k(PersArgs pa) {
  __shared__ __align__(16) ushort lA[3][4096];
  __shared__ __align__(16) ushort lB[3][4096];
  int gen = 0;
  int lane = threadIdx.x & 63;
  int wv = threadIdx.x >> 6;

  for (int l = 0; l < 12; ++l) {
    int P = NN >> (l + 1);
    int C = P << 1;
    int offL = 8192 - (8192 >> l), offP = 8192 - (8192 >> (l + 1));
    int qrt = (P + 127) >> 7, krt = (C + 127) >> 7;
    int nQ = qrt * 8 * 2, nKV = krt * 16 * 2, nA = nQ + nKV;
    int cnt = (nA + NBLK - 1) / NBLK;
    int t0 = blockIdx.x * cnt, t1 = t0 + cnt; if (t1 > nA) t1 = nA;
    for (int t = t0; t < t1; ++t) {
      if (t < nQ) {
        int bz = t / (qrt * 8); int u2 = t - bz * (qrt * 8);
        int ty = u2 / qrt, tx = u2 - ty * qrt;
        gemm_tile_avg(pa.h + ((long)(bz * H_NODES + offL) << 10), P, pa.wt,
                      pa.qb + ((long)bz * P << 10), 1024, tx * 128, ty * 128, lA, lB);
      } else {
        int u = t - nQ;
        int bz = u / (krt * 16); int u2 = u - bz * (krt * 16);
        int ty = u2 / krt, tx = u2 - ty * krt;
        gemm_tile_g(pa.h + ((long)(bz * H_NODES + offL) << 10), C,
                    pa.wt + (size_t)1024 * 1024, nullptr,
                    pa.kv1 + (long)bz * C * 2048, 2048, 0, tx * 128, ty * 128, lA, lB);
      }
    }
    grid_bar(pa.bar, gen);
    int nM = 2 * P;
    for (int w = blockIdx.x * 4 + wv; w < nM; w += NBLK * 4)
      merge_one(pa.qb, pa.kv1, pa.mrg, P, w, lane);
    grid_bar(pa.bar, gen);
    int nO = qrt * 8 * 2;
    cnt = (nO + NBLK - 1) / NBLK;
    t0 = blockIdx.x * cnt; t1 = t0 + cnt; if (t1 > nO) t1 = nO;
    for (int t = t0; t < t1; ++t) {
      int bz = t / (qrt * 8); int u2 = t - bz * (qrt * 8);
      int ty = u2 / qrt, tx = u2 - ty * qrt;
      gemm_tile_g(pa.mrg + ((long)bz * P << 10), P,
                  pa.wt + (size_t)3 * 1024 * 1024, pa.boy,
                  pa.h + ((long)(bz * H_NODES + offP) << 10), 1024, 0, tx * 128, ty * 128, lA, lB);
    }
    grid_bar(pa.bar, gen);
  }

  // ---- stage 2: QKV projections
  {
    const int qrt = 32, krt = 64;
    int nQ = qrt * 8 * 2, nKV = krt * 16 * 2, nA = nQ + nKV;   // 512 + 2048
    int cnt = (nA + NBLK - 1) / NBLK;
    int t0 = blockIdx.x * cnt, t1 = t0 + cnt; if (t1 > nA) t1 = nA;
    for (int t = t0; t < t1; ++t) {
      if (t < nQ) {
        int bz = t / (qrt * 8); int u2 = t - bz * (qrt * 8);
        int ty = u2 / qrt, tx = u2 - ty * qrt;
        gemm_tile_g(pa.h + ((long)bz * H_NODES << 10), 4096,
                    pa.wt + (size_t)4 * 1024 * 1024, nullptr,
                    pa.Qx + ((long)bz * 4096 << 10), 1024, 0, tx * 128, ty * 128, lA, lB);
      } else {
        int u = t - nQ;
        int bz = u / (krt * 16); int u2 = u - bz * (krt * 16);
        int ty = u2 / krt, tx = u2 - ty * krt;
        gemm_tile_g(pa.h + ((long)bz * H_NODES << 10), H_NODES,
                    pa.wt + (size_t)5 * 1024 * 1024, nullptr,
                    pa.KVa + (long)bz * H_NODES * 2048, 2048, 0, tx * 128, ty * 128, lA, lB);
      }
    }
    grid_bar(pa.bar, gen);
    for (int w = blockIdx.x * 4 + wv; w < 8192; w += NBLK * 4)
      attn_one(pa.Qx, pa.KVa, pa.aout, w, lane);
    grid_bar(pa.bar, gen);
    int nO = 32 * 8 * 2;
    cnt = (nO + NBLK - 1) / NBLK;
    t0 = blockIdx.x * cnt; t1 = t0 + cnt; if (t1 > nO) t1 = nO;
    for (int t = t0; t < t1; ++t) {
      int bz = t / (32 * 8); int u2 = t - bz * (32 * 8);
      int ty = u2 / 32, tx = u2 - ty * 32;
      gemm_tile_g(pa.aout + ((long)bz * 4096 << 10), 4096,
                  pa.wt + (size_t)7 * 1024 * 1024, pa.box,
                  pa.outp + (long)bz * 4096 * 1024, 1024, 2, tx * 128, ty * 128, lA, lB);
    }
  }
}

extern "C" void kernel_launch(void* const* d_in, const int* in_sizes, int n_in,
                              void* d_out, int out_size, void* d_ws, size_t ws_size,
                              hipStream_t stream) {
  const float* x    = (const float*)d_in[0];
  const float* Wq_y = (const float*)d_in[1];
  const float* Wk_y = (const float*)d_in[2];
  const float* Wv_y = (const float*)d_in[3];
  const float* Wo_y = (const float*)d_in[4];
  const float* bo_y = (const float*)d_in[5];
  const float* Wq_x = (const float*)d_in[6];
  const float* Wk_x = (const float*)d_in[7];
  const float* Wv_x = (const float*)d_in[8];
  const float* Wo_x = (const float*)d_in[9];
  const float* bo_x = (const float*)d_in[10];

  ushort* wt  = (ushort*)d_ws;                              // 8 x 1M bf16 weights^T
  ushort* h   = wt + (size_t)8 * 1024 * 1024;               // [B][8191][1024]
  ushort* reg = h + (size_t)2 * H_NODES * DIMC;
  // stage-1 view
  ushort* qb  = reg;                                        // [B][2048][1024] max
  ushort* kv1 = qb + (size_t)2 * 2048 * DIMC;               // [B][4096][2048] max
  ushort* mrg = kv1 + (size_t)2 * 4096 * 2048;              // [B][2048][1024] max
  // stage-2 view (stage-1 dead by then)
  ushort* Qx   = reg;                                       // [B][4096][1024]
  ushort* KVa  = Qx + (size_t)2 * 4096 * DIMC;              // [B][8191][2048]
  ushort* aout = KVa + (size_t)2 * H_NODES * 2048;          // [B][4096][1024]
  ushort* wsend = aout + (size_t)2 * 4096 * DIMC;
  int* bar = (int*)wsend;

  size_t need = (size_t)((char*)(bar + 16) - (char*)d_ws);
  if (ws_size < need) return;

  WPtrs wp;
  wp.w[0] = Wq_y; wp.w[1] = Wk_y; wp.w[2] = Wv_y; wp.w[3] = Wo_y;
  wp.w[4] = Wq_x; wp.w[5] = Wk_x; wp.w[6] = Wv_x; wp.w[7] = Wo_x;
  transpose_w_k<<<dim3(32, 32, 8), dim3(32, 8), 0, stream>>>(wp, wt);
  cvt_x_k<<<8192, 256, 0, stream>>>(x, h, bar);

  PersArgs pa;
  pa.h = h; pa.wt = wt; pa.boy = bo_y; pa.box = bo_x;
  pa.qb = qb; pa.kv1 = kv1; pa.mrg = mrg;
  pa.Qx = Qx; pa.KVa = KVa; pa.aout = aout; pa.outp = (float*)d_out;
  pa.bar = bar;
  tree_pers_k<<<NBLK, 256, 0, stream>>>(pa);
}

// Round 5
// 1607.820 us; speedup vs baseline: 3.6292x; 3.6292x over previous
//
#include <hip/hip_runtime.h>
#include <stdint.h>

#define H_NODES 8191
#define NN 4096
#define DIMC 1024

typedef __bf16 bf16x8 __attribute__((ext_vector_type(8)));
typedef float f32x4 __attribute__((ext_vector_type(4)));

__device__ __forceinline__ float b2f(ushort u) {
  union { uint32_t i; float f; } x; x.i = ((uint32_t)u) << 16; return x.f;
}
__device__ __forceinline__ ushort f2b(float f) {
  union { float f; uint32_t i; } x; x.f = f;
  uint32_t r = x.i + 0x7FFFu + ((x.i >> 16) & 1u);
  return (ushort)(r >> 16);
}
__device__ __forceinline__ void load16f(const ushort* p, float* f) {
  const uint32_t* w = (const uint32_t*)p;
  #pragma unroll
  for (int i = 0; i < 8; ++i) {
    uint32_t v = w[i];
    f[2 * i]     = b2f((ushort)(v & 0xffff));
    f[2 * i + 1] = b2f((ushort)(v >> 16));
  }
}
__device__ __forceinline__ void store16b(ushort* p, const float* f) {
  uint32_t w[8];
  #pragma unroll
  for (int i = 0; i < 8; ++i)
    w[i] = (uint32_t)f2b(f[2 * i]) | ((uint32_t)f2b(f[2 * i + 1]) << 16);
  *(uint4*)p = *(const uint4*)&w[0];
  *(uint4*)(p + 8) = *(const uint4*)&w[4];
}

// ---------------- weight transpose + fp32->bf16
struct WPtrs { const float* w[8]; };

__global__ void __launch_bounds__(256) transpose_w_k(WPtrs wp, ushort* __restrict__ dst) {
  __shared__ float t[32][33];
  const float* src = wp.w[blockIdx.z];
  int c0 = blockIdx.x * 32, r0 = blockIdx.y * 32;
  int tx = threadIdx.x, ty = threadIdx.y;
  #pragma unroll
  for (int i = ty; i < 32; i += 8)
    t[i][tx] = src[(long)(r0 + i) * DIMC + c0 + tx];
  __syncthreads();
  ushort* d = dst + (long)blockIdx.z * DIMC * DIMC;
  #pragma unroll
  for (int i = ty; i < 32; i += 8)
    d[(long)(c0 + i) * DIMC + r0 + tx] = f2b(t[tx][i]);
}

// ---------------- x fp32 -> h leaf rows (bf16)
__global__ void __launch_bounds__(256) cvt_x_k(const float* __restrict__ x, ushort* __restrict__ h) {
  long t = (long)blockIdx.x * 256 + threadIdx.x;
  long i = t << 2;
  if (i >= (long)2 * NN * DIMC) return;
  long row = i >> 10;
  int col = (int)(i & 1023);
  long b = row >> 12;
  long n = row & 4095;
  float4 v = *(const float4*)(x + i);
  ushort* d = h + ((b * H_NODES + n) << 10) + col;
  uint2 pk;
  pk.x = (uint32_t)f2b(v.x) | ((uint32_t)f2b(v.y) << 16);
  pk.y = (uint32_t)f2b(v.z) | ((uint32_t)f2b(v.w) << 16);
  *(uint2*)d = pk;
}

// ---------------- shared MFMA inner step (swizzled LDS frags, 16 MFMA)
__device__ __forceinline__ void mfma_step(const ushort* a, const ushort* b,
    f32x4 (&acc)[4][4], int wr, int wc, int rr, int g4) {
  bf16x8 af[4], bfr[4];
  #pragma unroll
  for (int m = 0; m < 4; ++m) {
    int r = wr * 64 + m * 16 + rr;
    int slot = g4 ^ ((r >> 1) & 3);
    af[m] = *reinterpret_cast<const bf16x8*>(a + r * 32 + slot * 8);
  }
  #pragma unroll
  for (int n = 0; n < 4; ++n) {
    int r = wc * 64 + n * 16 + rr;
    int slot = g4 ^ ((r >> 1) & 3);
    bfr[n] = *reinterpret_cast<const bf16x8*>(b + r * 32 + slot * 8);
  }
  __builtin_amdgcn_s_setprio(1);
  #pragma unroll
  for (int m = 0; m < 4; ++m)
    #pragma unroll
    for (int n = 0; n < 4; ++n)
      acc[m][n] = __builtin_amdgcn_mfma_f32_16x16x32_bf16(af[m], bfr[n], acc[m][n], 0, 0, 0);
  __builtin_amdgcn_s_setprio(0);
}

__device__ __forceinline__ void cwrite(f32x4 (&acc)[4][4], const float* bias,
    void* Cp, int ldc, int M, int outMode, int row0, int col0, int wr, int wc, int lane) {
  int rr = lane & 15, rq = lane >> 4;
  #pragma unroll
  for (int n = 0; n < 4; ++n) {
    int col = col0 + wc * 64 + n * 16 + rr;
    float bv = bias ? bias[col] : 0.0f;
    #pragma unroll
    for (int m = 0; m < 4; ++m) {
      int gr0 = row0 + wr * 64 + m * 16 + rq * 4;
      #pragma unroll
      for (int r = 0; r < 4; ++r) {
        int gr = gr0 + r;
        if (gr < M) {
          float vv = acc[m][n][r] + bv;
          long o = (long)gr * ldc + col;
          if (outMode == 2) ((float*)Cp)[o] = vv;
          else ((ushort*)Cp)[o] = f2b(vv);
        }
      }
    }
  }
}

// ---------------- 128x128 pipelined GEMM tile, gload_lds staging (3-buf)
__device__ void gemm_tile_g(const ushort* __restrict__ A, int M,
    const ushort* __restrict__ Bt, const float* bias, void* Cp, int ldc, int outMode,
    int row0, int col0, ushort (*lA)[4096], ushort (*lB)[4096]) {
  int tid = threadIdx.x, wave = tid >> 6, lane = tid & 63;
  int wr = wave >> 1, wc = wave & 1;
  f32x4 acc[4][4];
  #pragma unroll
  for (int m = 0; m < 4; ++m)
    #pragma unroll
    for (int n = 0; n < 4; ++n) acc[m][n] = (f32x4){0.f, 0.f, 0.f, 0.f};

  auto stage = [&](int kt, int buf) {
    #pragma unroll
    for (int j = 0; j < 2; ++j) {
      int s = wave * 128 + j * 64 + lane;
      int r = s >> 2;
      int g = (s & 3) ^ ((r >> 1) & 3);
      int gr = row0 + r; gr = (gr < M) ? gr : (M - 1);
      __builtin_amdgcn_global_load_lds(
          (const __attribute__((address_space(1))) void*)(uintptr_t)(A + (long)gr * DIMC + kt * 32 + g * 8),
          (__attribute__((address_space(3))) void*)(uint32_t)(uintptr_t)(lA[buf] + s * 8), 16, 0, 0);
      __builtin_amdgcn_global_load_lds(
          (const __attribute__((address_space(1))) void*)(uintptr_t)(Bt + (long)(col0 + r) * DIMC + kt * 32 + g * 8),
          (__attribute__((address_space(3))) void*)(uint32_t)(uintptr_t)(lB[buf] + s * 8), 16, 0, 0);
    }
  };
  stage(0, 0); stage(1, 1);
  asm volatile("s_waitcnt vmcnt(4)" ::: "memory");
  __builtin_amdgcn_s_barrier();

  int rr = lane & 15, g4 = lane >> 4;
  for (int kt = 0; kt < 32; ++kt) {
    int cur = kt % 3;
    if (kt + 2 < 32) stage(kt + 2, (kt + 2) % 3);
    mfma_step(lA[cur], lB[cur], acc, wr, wc, rr, g4);
    if (kt < 30) { asm volatile("s_waitcnt vmcnt(4)" ::: "memory"); }
    else         { asm volatile("s_waitcnt vmcnt(0)" ::: "memory"); }
    if (kt < 31) __builtin_amdgcn_s_barrier();
  }
  cwrite(acc, bias, Cp, ldc, M, outMode, row0, col0, wr, wc, lane);
}

// ---------------- 128x128 GEMM tile with A = 0.5*(child0+child1), reg-staged (2-buf)
__device__ void gemm_tile_avg(const ushort* __restrict__ Hc, int M,
    const ushort* __restrict__ Bt, ushort* Cp, int ldc,
    int row0, int col0, ushort (*lA)[4096], ushort (*lB)[4096]) {
  int tid = threadIdx.x, wave = tid >> 6, lane = tid & 63;
  int wr = wave >> 1, wc = wave & 1;
  f32x4 acc[4][4];
  #pragma unroll
  for (int m = 0; m < 4; ++m)
    #pragma unroll
    for (int n = 0; n < 4; ++n) acc[m][n] = (f32x4){0.f, 0.f, 0.f, 0.f};

  uint4 ra0[2], ra1[2], rb[2];
  auto loadS = [&](int kt) {
    #pragma unroll
    for (int j = 0; j < 2; ++j) {
      int s = wave * 128 + j * 64 + lane;
      int r = s >> 2;
      int g = (s & 3) ^ ((r >> 1) & 3);
      int pr = row0 + r; pr = (pr < M) ? pr : (M - 1);
      const ushort* c0 = Hc + ((long)(2 * pr) << 10) + kt * 32 + g * 8;
      ra0[j] = *(const uint4*)c0;
      ra1[j] = *(const uint4*)(c0 + DIMC);
      rb[j] = *(const uint4*)(Bt + (long)(col0 + r) * DIMC + kt * 32 + g * 8);
    }
  };
  auto writeS = [&](int buf) {
    #pragma unroll
    for (int j = 0; j < 2; ++j) {
      int s = wave * 128 + j * 64 + lane;
      uint32_t ow[4];
      const uint32_t* pa = (const uint32_t*)&ra0[j];
      const uint32_t* pb = (const uint32_t*)&ra1[j];
      #pragma unroll
      for (int i = 0; i < 4; ++i) {
        float x0 = b2f((ushort)(pa[i] & 0xffff)), x1 = b2f((ushort)(pa[i] >> 16));
        float y0 = b2f((ushort)(pb[i] & 0xffff)), y1 = b2f((ushort)(pb[i] >> 16));
        ow[i] = (uint32_t)f2b(0.5f * (x0 + y0)) | ((uint32_t)f2b(0.5f * (x1 + y1)) << 16);
      }
      *(uint4*)(lA[buf] + s * 8) = *(const uint4*)ow;
      *(uint4*)(lB[buf] + s * 8) = rb[j];
    }
  };
  loadS(0); writeS(0); loadS(1);
  asm volatile("s_waitcnt lgkmcnt(0)" ::: "memory");
  __builtin_amdgcn_s_barrier();

  int rr = lane & 15, g4 = lane >> 4;
  for (int kt = 0; kt < 32; ++kt) {
    if (kt + 1 < 32) writeS((kt + 1) & 1);
    if (kt + 2 < 32) loadS(kt + 2);
    mfma_step(lA[kt & 1], lB[kt & 1], acc, wr, wc, rr, g4);
    asm volatile("s_waitcnt lgkmcnt(0)" ::: "memory");
    if (kt < 31) __builtin_amdgcn_s_barrier();
  }
  cwrite(acc, nullptr, Cp, ldc, M, 0, row0, col0, wr, wc, lane);
}

// ---------------- stage-1 dispatch A: [avg+Q GEMM] plus [KV GEMM] in one launch
__global__ void __launch_bounds__(256) qkv_level_k(const ushort* __restrict__ h,
    const ushort* __restrict__ wtq, const ushort* __restrict__ wtkv,
    ushort* __restrict__ qb, ushort* __restrict__ kv1,
    int P, int offL, int qrt, int krt, int nQ) {
  __shared__ __align__(16) ushort lA[3][4096];
  __shared__ __align__(16) ushort lB[3][4096];
  int t = blockIdx.x;
  if (t < nQ) {
    int per = qrt * 8;
    int bz = t / per; int u2 = t - bz * per;
    int ty = u2 / qrt, tx = u2 - ty * qrt;
    gemm_tile_avg(h + ((long)(bz * H_NODES + offL) << 10), P, wtq,
                  qb + ((long)bz * P << 10), 1024, tx * 128, ty * 128, lA, lB);
  } else {
    int u = t - nQ;
    int per = krt * 16;
    int bz = u / per; int u2 = u - bz * per;
    int ty = u2 / krt, tx = u2 - ty * krt;
    gemm_tile_g(h + ((long)(bz * H_NODES + offL) << 10), 2 * P, wtkv, nullptr,
                kv1 + (long)bz * 2 * P * 2048, 2048, 0, tx * 128, ty * 128, lA, lB);
  }
}

// ---------------- stage-1 dispatch B: merge fused into O-GEMM A-path
__global__ void __launch_bounds__(256) mo_level_k(const ushort* __restrict__ qb,
    const ushort* __restrict__ kv1, const ushort* __restrict__ wto,
    const float* __restrict__ boy, ushort* __restrict__ h,
    int P, int offP, int qrt) {
  __shared__ __align__(16) ushort lA[2][4096];
  __shared__ __align__(16) ushort lB[2][4096];
  __shared__ float2 wgt[128][16];
  int per = qrt * 8;
  int t = blockIdx.x;
  int bz = t / per; int u2 = t - bz * per;
  int ty = u2 / qrt, tx = u2 - ty * qrt;
  int row0 = tx * 128, col0 = ty * 128;
  int C2 = 2 * P;
  int tid = threadIdx.x;

  // --- weight phase: softmax over the 2 children, per (p,row in tile, head)
  for (int id = tid; id < 2048; id += 256) {
    int p = id >> 4, hh = id & 15;
    int gp = row0 + p; if (gp >= P) gp = P - 1;
    const ushort* qr = qb + (((long)(bz * P + gp)) << 10) + hh * 64;
    const ushort* k0 = kv1 + ((long)(bz * C2 + 2 * gp)) * 2048 + hh * 64;
    const ushort* k1 = k0 + 2048;
    float a0 = 0.f, a1 = 0.f;
    #pragma unroll
    for (int c = 0; c < 4; ++c) {
      float qf[16], k0f[16], k1f[16];
      load16f(qr + c * 16, qf);
      load16f(k0 + c * 16, k0f);
      load16f(k1 + c * 16, k1f);
      #pragma unroll
      for (int j = 0; j < 16; ++j) { a0 += qf[j] * k0f[j]; a1 += qf[j] * k1f[j]; }
    }
    float s0 = a0 * 0.125f, s1 = a1 * 0.125f;
    float mm = fmaxf(s0, s1);
    float e0 = expf(s0 - mm), e1 = expf(s1 - mm);
    float inv = 1.0f / (e0 + e1 + 1e-9f);
    wgt[p][hh] = make_float2(e0 * inv, e1 * inv);
  }
  __syncthreads();

  int wave = tid >> 6, lane = tid & 63;
  int wr = wave >> 1, wc = wave & 1;
  f32x4 acc[4][4];
  #pragma unroll
  for (int m = 0; m < 4; ++m)
    #pragma unroll
    for (int n = 0; n < 4; ++n) acc[m][n] = (f32x4){0.f, 0.f, 0.f, 0.f};

  uint4 ra0[2], ra1[2], rb[2];
  auto loadS = [&](int kt) {
    #pragma unroll
    for (int j = 0; j < 2; ++j) {
      int s = wave * 128 + j * 64 + lane;
      int r = s >> 2;
      int g = (s & 3) ^ ((r >> 1) & 3);
      int gp = row0 + r; if (gp >= P) gp = P - 1;
      const ushort* vb = kv1 + ((long)(bz * C2 + 2 * gp)) * 2048 + 1024 + kt * 32 + g * 8;
      ra0[j] = *(const uint4*)vb;
      ra1[j] = *(const uint4*)(vb + 2048);
      rb[j] = *(const uint4*)(wto + (long)(col0 + r) * DIMC + kt * 32 + g * 8);
    }
  };
  auto writeS = [&](int kt, int buf) {
    #pragma unroll
    for (int j = 0; j < 2; ++j) {
      int s = wave * 128 + j * 64 + lane;
      int r = s >> 2;
      int g = (s & 3) ^ ((r >> 1) & 3);
      float2 wp = wgt[r][(kt * 32 + g * 8) >> 6];
      uint32_t ow[4];
      const uint32_t* pa = (const uint32_t*)&ra0[j];
      const uint32_t* pb = (const uint32_t*)&ra1[j];
      #pragma unroll
      for (int i = 0; i < 4; ++i) {
        float x0 = b2f((ushort)(pa[i] & 0xffff)), x1 = b2f((ushort)(pa[i] >> 16));
        float y0 = b2f((ushort)(pb[i] & 0xffff)), y1 = b2f((ushort)(pb[i] >> 16));
        ow[i] = (uint32_t)f2b(wp.x * x0 + wp.y * y0)
              | ((uint32_t)f2b(wp.x * x1 + wp.y * y1) << 16);
      }
      *(uint4*)(lA[buf] + s * 8) = *(const uint4*)ow;
      *(uint4*)(lB[buf] + s * 8) = rb[j];
    }
  };
  loadS(0); writeS(0, 0); loadS(1);
  asm volatile("s_waitcnt lgkmcnt(0)" ::: "memory");
  __builtin_amdgcn_s_barrier();

  int rr = lane & 15, g4 = lane >> 4;
  for (int kt = 0; kt < 32; ++kt) {
    if (kt + 1 < 32) writeS(kt + 1, (kt + 1) & 1);
    if (kt + 2 < 32) loadS(kt + 2);
    mfma_step(lA[kt & 1], lB[kt & 1], acc, wr, wc, rr, g4);
    asm volatile("s_waitcnt lgkmcnt(0)" ::: "memory");
    if (kt < 31) __builtin_amdgcn_s_barrier();
  }
  cwrite(acc, boy, h + ((long)(bz * H_NODES + offP) << 10), 1024, P, 1,
         row0, col0, wr, wc, lane);
}

// ---------------- stage-2 generic GEMM launch (two descriptors per launch)
struct GemmDesc {
  const ushort* A; long sAb;
  const ushort* Bt;
  const float* bias;
  void* C; long sCb; int ldc;
  int M; int outMode;
  int tX, tY;
};

__global__ void __launch_bounds__(256) gemm_multi(GemmDesc d0, GemmDesc d1, int t0) {
  __shared__ __align__(16) ushort lA[3][4096];
  __shared__ __align__(16) ushort lB[3][4096];
  int t = blockIdx.x;
  const GemmDesc& d = (t < t0) ? d0 : d1;
  int u = (t < t0) ? t : t - t0;
  int per = d.tX * d.tY;
  int bz = u / per;
  int rem = u - bz * per;
  int ty = rem / d.tX;
  int tx = rem - ty * d.tX;
  void* Cb = (d.outMode == 2) ? (void*)((float*)d.C + (long)bz * d.sCb)
                              : (void*)((ushort*)d.C + (long)bz * d.sCb);
  gemm_tile_g(d.A + (long)bz * d.sAb, d.M, d.Bt, d.bias, Cb, d.ldc, d.outMode,
              tx * 128, ty * 128, lA, lB);
}

// ---------------- stage-2 gather attention: one wave per (b,n), all heads
__global__ void __launch_bounds__(256) attn_x2_k(const ushort* __restrict__ Q,
    const ushort* __restrict__ KV, ushort* __restrict__ outp) {
  int wave = threadIdx.x >> 6, lane = threadIdx.x & 63;
  long w = (long)blockIdx.x * 4 + wave;
  int n = (int)(w & 4095);
  int b = (int)(w >> 12);
  const ushort* KVb = KV + (long)b * H_NODES * 2048;
  float qf[16];
  load16f(Q + (((long)b * NN + n) << 10) + lane * 16, qf);
  int nb[13];
  nb[0] = n;
  #pragma unroll
  for (int l = 0; l < 12; ++l) nb[1 + l] = (8192 - (8192 >> l)) + ((n >> l) ^ 1);
  float s[13];
  #pragma unroll
  for (int i = 0; i < 13; ++i) {
    float kf[16];
    load16f(KVb + (long)nb[i] * 2048 + lane * 16, kf);
    float d = 0.f;
    #pragma unroll
    for (int j = 0; j < 16; ++j) d += qf[j] * kf[j];
    d += __shfl_xor(d, 1);
    d += __shfl_xor(d, 2);
    s[i] = d * 0.125f;
  }
  #pragma unroll
  for (int l = 0; l < 12; ++l)
    if (((n >> l) & 1) == 0) s[1 + l] = -__builtin_inff();
  float mm = s[0];
  #pragma unroll
  for (int i = 1; i < 13; ++i) mm = fmaxf(mm, s[i]);
  float e[13], sum = 0.f;
  #pragma unroll
  for (int i = 0; i < 13; ++i) { e[i] = expf(s[i] - mm); sum += e[i]; }
  float inv = 1.0f / sum;
  float ov[16];
  #pragma unroll
  for (int j = 0; j < 16; ++j) ov[j] = 0.f;
  #pragma unroll
  for (int i = 0; i < 13; ++i) {
    float wgt = e[i] * inv;
    float vf[16];
    load16f(KVb + (long)nb[i] * 2048 + 1024 + lane * 16, vf);
    #pragma unroll
    for (int j = 0; j < 16; ++j) ov[j] += wgt * vf[j];
  }
  store16b(outp + (((long)b * NN + n) << 10) + lane * 16, ov);
}

extern "C" void kernel_launch(void* const* d_in, const int* in_sizes, int n_in,
                              void* d_out, int out_size, void* d_ws, size_t ws_size,
                              hipStream_t stream) {
  const float* x    = (const float*)d_in[0];
  const float* Wq_y = (const float*)d_in[1];
  const float* Wk_y = (const float*)d_in[2];
  const float* Wv_y = (const float*)d_in[3];
  const float* Wo_y = (const float*)d_in[4];
  const float* bo_y = (const float*)d_in[5];
  const float* Wq_x = (const float*)d_in[6];
  const float* Wk_x = (const float*)d_in[7];
  const float* Wv_x = (const float*)d_in[8];
  const float* Wo_x = (const float*)d_in[9];
  const float* bo_x = (const float*)d_in[10];

  ushort* wt  = (ushort*)d_ws;                              // 8 x 1M bf16 weights^T
  ushort* h   = wt + (size_t)8 * 1024 * 1024;               // [B][8191][1024]
  ushort* reg = h + (size_t)2 * H_NODES * DIMC;
  // stage-1 view
  ushort* qb  = reg;                                        // [B][2048][1024] max
  ushort* kv1 = qb + (size_t)2 * 2048 * DIMC;               // [B][4096][2048] max
  // stage-2 view (stage-1 dead by then)
  ushort* Qx   = reg;                                       // [B][4096][1024]
  ushort* KVa  = Qx + (size_t)2 * 4096 * DIMC;              // [B][8191][2048]
  ushort* aout = KVa + (size_t)2 * H_NODES * 2048;          // [B][4096][1024]

  size_t need = ((size_t)8 * 1024 * 1024 + (size_t)2 * H_NODES * DIMC +
                 (size_t)2 * 4096 * DIMC + (size_t)2 * H_NODES * 2048 +
                 (size_t)2 * 4096 * DIMC) * 2;
  if (ws_size < need) return;

  WPtrs wp;
  wp.w[0] = Wq_y; wp.w[1] = Wk_y; wp.w[2] = Wv_y; wp.w[3] = Wo_y;
  wp.w[4] = Wq_x; wp.w[5] = Wk_x; wp.w[6] = Wv_x; wp.w[7] = Wo_x;
  transpose_w_k<<<dim3(32, 32, 8), dim3(32, 8), 0, stream>>>(wp, wt);
  cvt_x_k<<<8192, 256, 0, stream>>>(x, h);

  for (int l = 0; l < 12; ++l) {
    int P = NN >> (l + 1);
    int offL = 8192 - (8192 >> l);
    int offP = 8192 - (8192 >> (l + 1));
    int qrt = (P + 127) >> 7, krt = (2 * P + 127) >> 7;
    int nQ = qrt * 8 * 2, nKV = krt * 16 * 2;
    qkv_level_k<<<nQ + nKV, 256, 0, stream>>>(
        h, wt, wt + (size_t)1 * 1024 * 1024, qb, kv1, P, offL, qrt, krt, nQ);
    mo_level_k<<<qrt * 8 * 2, 256, 0, stream>>>(
        qb, kv1, wt + (size_t)3 * 1024 * 1024, bo_y, h, P, offP, qrt);
  }

  // stage 2
  auto mk128 = [](const ushort* A, long sAb, const ushort* Bt, const float* bias,
                  void* C, long sCb, int ldc, int M, int outMode, int tY) {
    GemmDesc d; d.A = A; d.sAb = sAb; d.Bt = Bt; d.bias = bias; d.C = C; d.sCb = sCb;
    d.ldc = ldc; d.M = M; d.outMode = outMode; d.tX = (M + 127) / 128; d.tY = tY;
    return d;
  };
  GemmDesc dqx = mk128(h, (long)H_NODES * DIMC, wt + (size_t)4 * 1024 * 1024, nullptr,
                       Qx, (long)4096 * DIMC, DIMC, 4096, 0, 8);
  GemmDesc dkva = mk128(h, (long)H_NODES * DIMC, wt + (size_t)5 * 1024 * 1024, nullptr,
                        KVa, (long)H_NODES * 2048, 2048, H_NODES, 0, 16);
  int t0 = dqx.tX * dqx.tY * 2, t1 = dkva.tX * dkva.tY * 2;
  gemm_multi<<<t0 + t1, 256, 0, stream>>>(dqx, dkva, t0);
  attn_x2_k<<<2048, 256, 0, stream>>>(Qx, KVa, aout);
  GemmDesc dox = mk128(aout, (long)4096 * DIMC, wt + (size_t)7 * 1024 * 1024, bo_x,
                       d_out, (long)4096 * DIMC, DIMC, 4096, 2, 8);
  gemm_multi<<<dox.tX * dox.tY * 2, 256, 0, stream>>>(dox, dox, dox.tX * dox.tY * 2);
}

// Round 6
// 1325.695 us; speedup vs baseline: 4.4015x; 1.2128x over previous
//
#include <hip/hip_runtime.h>
#include <stdint.h>

#define H_NODES 8191
#define NN 4096
#define DIMC 1024

typedef __bf16 bf16x8 __attribute__((ext_vector_type(8)));
typedef float f32x4 __attribute__((ext_vector_type(4)));

__device__ __forceinline__ float b2f(ushort u) {
  union { uint32_t i; float f; } x; x.i = ((uint32_t)u) << 16; return x.f;
}
__device__ __forceinline__ ushort f2b(float f) {
  union { float f; uint32_t i; } x; x.f = f;
  uint32_t r = x.i + 0x7FFFu + ((x.i >> 16) & 1u);
  return (ushort)(r >> 16);
}
__device__ __forceinline__ void load16f(const ushort* p, float* f) {
  const uint32_t* w = (const uint32_t*)p;
  #pragma unroll
  for (int i = 0; i < 8; ++i) {
    uint32_t v = w[i];
    f[2 * i]     = b2f((ushort)(v & 0xffff));
    f[2 * i + 1] = b2f((ushort)(v >> 16));
  }
}
__device__ __forceinline__ void store16b(ushort* p, const float* f) {
  uint32_t w[8];
  #pragma unroll
  for (int i = 0; i < 8; ++i)
    w[i] = (uint32_t)f2b(f[2 * i]) | ((uint32_t)f2b(f[2 * i + 1]) << 16);
  *(uint4*)p = *(const uint4*)&w[0];
  *(uint4*)(p + 8) = *(const uint4*)&w[4];
}

// ---------------- weight transpose + fp32->bf16 : dst[z][n][k] = bf16(W_z[k][n])
struct WPtrs { const float* w[8]; };

__global__ void __launch_bounds__(256) transpose_w_k(WPtrs wp, ushort* __restrict__ dst) {
  __shared__ float t[32][33];
  const float* src = wp.w[blockIdx.z];
  int c0 = blockIdx.x * 32, r0 = blockIdx.y * 32;
  int tx = threadIdx.x, ty = threadIdx.y;
  #pragma unroll
  for (int i = ty; i < 32; i += 8)
    t[i][tx] = src[(long)(r0 + i) * DIMC + c0 + tx];
  __syncthreads();
  ushort* d = dst + (long)blockIdx.z * DIMC * DIMC;
  #pragma unroll
  for (int i = ty; i < 32; i += 8)
    d[(long)(c0 + i) * DIMC + r0 + tx] = f2b(t[tx][i]);
}

// ---------------- x fp32 -> h leaf rows (bf16)
__global__ void __launch_bounds__(256) cvt_x_k(const float* __restrict__ x, ushort* __restrict__ h) {
  long t = (long)blockIdx.x * 256 + threadIdx.x;
  long i = t << 2;
  if (i >= (long)2 * NN * DIMC) return;
  long row = i >> 10;
  int col = (int)(i & 1023);
  long b = row >> 12;
  long n = row & 4095;
  float4 v = *(const float4*)(x + i);
  ushort* d = h + ((b * H_NODES + n) << 10) + col;
  uint2 pk;
  pk.x = (uint32_t)f2b(v.x) | ((uint32_t)f2b(v.y) << 16);
  pk.y = (uint32_t)f2b(v.z) | ((uint32_t)f2b(v.w) << 16);
  *(uint2*)d = pk;
}

// ---------------- GEMM descriptor
struct GemmDesc {
  const ushort* A; long sAb;
  const ushort* Bt;
  const float* bias;
  void* C; long sCb; int ldc;
  int M; int outMode;   // 0 bf16, 1 bf16+bias, 2 fp32+bias
  int tX, tY;
};

// ---------------- 128x128 pipelined GEMM tile (3-buf, gload_lds) — FORCE-INLINED
__device__ __forceinline__ void stage_tile(const GemmDesc& d, const ushort* Ab,
    int row0, int col0, ushort* lA, ushort* lB, int kt, int wave, int lane) {
  #pragma unroll
  for (int j = 0; j < 2; ++j) {
    int s = wave * 128 + j * 64 + lane;
    int r = s >> 2;
    int g = (s & 3) ^ ((r >> 1) & 3);       // pre-swizzled source k-block
    int gr = row0 + r; gr = (gr < d.M) ? gr : (d.M - 1);
    const ushort* srcA = Ab + (long)gr * DIMC + kt * 32 + g * 8;
    __builtin_amdgcn_global_load_lds(
        (const __attribute__((address_space(1))) void*)(uintptr_t)srcA,
        (__attribute__((address_space(3))) void*)(uint32_t)(uintptr_t)(lA + (wave * 128 + j * 64) * 8),
        16, 0, 0);
    const ushort* srcB = d.Bt + (long)(col0 + r) * DIMC + kt * 32 + g * 8;
    __builtin_amdgcn_global_load_lds(
        (const __attribute__((address_space(1))) void*)(uintptr_t)srcB,
        (__attribute__((address_space(3))) void*)(uint32_t)(uintptr_t)(lB + (wave * 128 + j * 64) * 8),
        16, 0, 0);
  }
}

__device__ __forceinline__ void gemm_tile(const GemmDesc& d, int bz, int row0, int col0,
    ushort (*lA)[4096], ushort (*lB)[4096], int tid) {
  const ushort* Ab = d.A + (long)bz * d.sAb;
  int wave = tid >> 6, lane = tid & 63;
  int wr = wave >> 1, wc = wave & 1;

  f32x4 acc[4][4];
  #pragma unroll
  for (int m = 0; m < 4; ++m)
    #pragma unroll
    for (int n = 0; n < 4; ++n) acc[m][n] = (f32x4){0.f, 0.f, 0.f, 0.f};

  stage_tile(d, Ab, row0, col0, lA[0], lB[0], 0, wave, lane);
  stage_tile(d, Ab, row0, col0, lA[1], lB[1], 1, wave, lane);
  asm volatile("s_waitcnt vmcnt(4)" ::: "memory");
  __builtin_amdgcn_s_barrier();

  int rr = lane & 15, g4 = lane >> 4;
  for (int kt = 0; kt < 32; ++kt) {
    int cur = kt % 3;
    if (kt + 2 < 32)
      stage_tile(d, Ab, row0, col0, lA[(kt + 2) % 3], lB[(kt + 2) % 3], kt + 2, wave, lane);
    bf16x8 af[4], bfr[4];
    #pragma unroll
    for (int m = 0; m < 4; ++m) {
      int r = wr * 64 + m * 16 + rr;
      int slot = g4 ^ ((r >> 1) & 3);
      af[m] = *reinterpret_cast<const bf16x8*>(&lA[cur][r * 32 + slot * 8]);
    }
    #pragma unroll
    for (int n = 0; n < 4; ++n) {
      int r = wc * 64 + n * 16 + rr;
      int slot = g4 ^ ((r >> 1) & 3);
      bfr[n] = *reinterpret_cast<const bf16x8*>(&lB[cur][r * 32 + slot * 8]);
    }
    __builtin_amdgcn_s_setprio(1);
    #pragma unroll
    for (int m = 0; m < 4; ++m)
      #pragma unroll
      for (int n = 0; n < 4; ++n)
        acc[m][n] = __builtin_amdgcn_mfma_f32_16x16x32_bf16(af[m], bfr[n], acc[m][n], 0, 0, 0);
    __builtin_amdgcn_s_setprio(0);
    if (kt < 30) { asm volatile("s_waitcnt vmcnt(4)" ::: "memory"); }
    else         { asm volatile("s_waitcnt vmcnt(0)" ::: "memory"); }
    if (kt < 31) __builtin_amdgcn_s_barrier();
  }

  int rq = lane >> 4;
  #pragma unroll
  for (int n = 0; n < 4; ++n) {
    int col = col0 + wc * 64 + n * 16 + rr;
    float bv = d.bias ? d.bias[col] : 0.0f;
    #pragma unroll
    for (int m = 0; m < 4; ++m) {
      int gr0 = row0 + wr * 64 + m * 16 + rq * 4;
      #pragma unroll
      for (int r = 0; r < 4; ++r) {
        int gr = gr0 + r;
        if (gr < d.M) {
          float vv = acc[m][n][r] + bv;
          long o = (long)bz * d.sCb + (long)gr * d.ldc + col;
          if (d.outMode == 2) ((float*)d.C)[o] = vv;
          else ((ushort*)d.C)[o] = f2b(vv);
        }
      }
    }
  }
}

// ---------------- 128x128 tile, A = 0.5*(child0+child1), reg-staged 2-buf — FORCE-INLINED
// d.A = children base (level offset applied), d.sAb = batch stride, d.M = P
__device__ __forceinline__ void gemm_tile_avg(const GemmDesc& d, int bz, int row0, int col0,
    ushort (*lA)[4096], ushort (*lB)[4096], int tid) {
  const ushort* Hc = d.A + (long)bz * d.sAb;
  int wave = tid >> 6, lane = tid & 63;
  int wr = wave >> 1, wc = wave & 1;
  f32x4 acc[4][4];
  #pragma unroll
  for (int m = 0; m < 4; ++m)
    #pragma unroll
    for (int n = 0; n < 4; ++n) acc[m][n] = (f32x4){0.f, 0.f, 0.f, 0.f};

  uint4 ra0[2], ra1[2], rb[2];
  auto loadS = [&](int kt) {
    #pragma unroll
    for (int j = 0; j < 2; ++j) {
      int s = wave * 128 + j * 64 + lane;
      int r = s >> 2;
      int g = (s & 3) ^ ((r >> 1) & 3);
      int pr = row0 + r; pr = (pr < d.M) ? pr : (d.M - 1);
      const ushort* c0 = Hc + ((long)(2 * pr) << 10) + kt * 32 + g * 8;
      ra0[j] = *(const uint4*)c0;
      ra1[j] = *(const uint4*)(c0 + DIMC);
      rb[j] = *(const uint4*)(d.Bt + (long)(col0 + r) * DIMC + kt * 32 + g * 8);
    }
  };
  auto writeS = [&](int buf) {
    #pragma unroll
    for (int j = 0; j < 2; ++j) {
      int s = wave * 128 + j * 64 + lane;
      uint32_t ow[4];
      const uint32_t* pa = (const uint32_t*)&ra0[j];
      const uint32_t* pb = (const uint32_t*)&ra1[j];
      #pragma unroll
      for (int i = 0; i < 4; ++i) {
        float x0 = b2f((ushort)(pa[i] & 0xffff)), x1 = b2f((ushort)(pa[i] >> 16));
        float y0 = b2f((ushort)(pb[i] & 0xffff)), y1 = b2f((ushort)(pb[i] >> 16));
        ow[i] = (uint32_t)f2b(0.5f * (x0 + y0)) | ((uint32_t)f2b(0.5f * (x1 + y1)) << 16);
      }
      *(uint4*)(lA[buf] + s * 8) = *(const uint4*)ow;
      *(uint4*)(lB[buf] + s * 8) = rb[j];
    }
  };
  loadS(0); writeS(0); loadS(1);
  asm volatile("s_waitcnt lgkmcnt(0)" ::: "memory");
  __builtin_amdgcn_s_barrier();

  int rr = lane & 15, g4 = lane >> 4;
  for (int kt = 0; kt < 32; ++kt) {
    if (kt + 1 < 32) writeS((kt + 1) & 1);
    if (kt + 2 < 32) loadS(kt + 2);
    bf16x8 af[4], bfr[4];
    #pragma unroll
    for (int m = 0; m < 4; ++m) {
      int r = wr * 64 + m * 16 + rr;
      int slot = g4 ^ ((r >> 1) & 3);
      af[m] = *reinterpret_cast<const bf16x8*>(&lA[kt & 1][r * 32 + slot * 8]);
    }
    #pragma unroll
    for (int n = 0; n < 4; ++n) {
      int r = wc * 64 + n * 16 + rr;
      int slot = g4 ^ ((r >> 1) & 3);
      bfr[n] = *reinterpret_cast<const bf16x8*>(&lB[kt & 1][r * 32 + slot * 8]);
    }
    __builtin_amdgcn_s_setprio(1);
    #pragma unroll
    for (int m = 0; m < 4; ++m)
      #pragma unroll
      for (int n = 0; n < 4; ++n)
        acc[m][n] = __builtin_amdgcn_mfma_f32_16x16x32_bf16(af[m], bfr[n], acc[m][n], 0, 0, 0);
    __builtin_amdgcn_s_setprio(0);
    asm volatile("s_waitcnt lgkmcnt(0)" ::: "memory");
    if (kt < 31) __builtin_amdgcn_s_barrier();
  }

  int rq = lane >> 4;
  #pragma unroll
  for (int n = 0; n < 4; ++n) {
    int col = col0 + wc * 64 + n * 16 + rr;
    #pragma unroll
    for (int m = 0; m < 4; ++m) {
      int gr0 = row0 + wr * 64 + m * 16 + rq * 4;
      #pragma unroll
      for (int r = 0; r < 4; ++r) {
        int gr = gr0 + r;
        if (gr < d.M)
          ((ushort*)d.C)[(long)bz * d.sCb + (long)gr * d.ldc + col] = f2b(acc[m][n][r]);
      }
    }
  }
}

// ---------------- stage-2 / generic GEMM launch (two descriptors per launch)
__global__ void __launch_bounds__(256) gemm_multi(GemmDesc d0, GemmDesc d1, int t0) {
  __shared__ __align__(16) ushort lA[3][4096];
  __shared__ __align__(16) ushort lB[3][4096];
  int t = blockIdx.x;
  const GemmDesc& d = (t < t0) ? d0 : d1;
  int u = (t < t0) ? t : t - t0;
  int per = d.tX * d.tY;
  int bz = u / per;
  int rem = u - bz * per;
  int ty = rem / d.tX;
  int tx = rem - ty * d.tX;
  gemm_tile(d, bz, tx * 128, ty * 128, lA, lB, threadIdx.x);
}

// ---------------- stage-1 dispatch A: [avg+Q GEMM] plus [KV GEMM] in one launch
__global__ void __launch_bounds__(256) qkv_level_k(GemmDesc dq, GemmDesc dkv, int t0) {
  __shared__ __align__(16) ushort lA[3][4096];
  __shared__ __align__(16) ushort lB[3][4096];
  int t = blockIdx.x;
  if (t < t0) {
    int per = dq.tX * dq.tY;
    int bz = t / per; int rem = t - bz * per;
    int ty = rem / dq.tX, tx = rem - ty * dq.tX;
    gemm_tile_avg(dq, bz, tx * 128, ty * 128, lA, lB, threadIdx.x);
  } else {
    int u = t - t0;
    int per = dkv.tX * dkv.tY;
    int bz = u / per; int rem = u - bz * per;
    int ty = rem / dkv.tX, tx = rem - ty * dkv.tX;
    gemm_tile(dkv, bz, tx * 128, ty * 128, lA, lB, threadIdx.x);
  }
}

// ---------------- stage-1 dispatch B: merge fused into O-GEMM A-path
__global__ void __launch_bounds__(256) mo_level_k(const ushort* __restrict__ qb,
    const ushort* __restrict__ kv1, const ushort* __restrict__ wto,
    const float* __restrict__ boy, ushort* __restrict__ h,
    int P, int offP, int qrt) {
  __shared__ __align__(16) ushort lA[2][4096];
  __shared__ __align__(16) ushort lB[2][4096];
  __shared__ float2 wgt[128][16];
  int per = qrt * 8;
  int t = blockIdx.x;
  int bz = t / per; int u2 = t - bz * per;
  int ty = u2 / qrt, tx = u2 - ty * qrt;
  int row0 = tx * 128, col0 = ty * 128;
  int C2 = 2 * P;
  int tid = threadIdx.x;

  // --- weight phase: 2-child softmax per (tile row, head)
  for (int id = tid; id < 2048; id += 256) {
    int p = id >> 4, hh = id & 15;
    int gp = row0 + p; if (gp >= P) gp = P - 1;
    const ushort* qr = qb + (((long)(bz * P + gp)) << 10) + hh * 64;
    const ushort* k0 = kv1 + ((long)(bz * C2 + 2 * gp)) * 2048 + hh * 64;
    const ushort* k1 = k0 + 2048;
    float a0 = 0.f, a1 = 0.f;
    #pragma unroll
    for (int c = 0; c < 4; ++c) {
      float qf[16], k0f[16], k1f[16];
      load16f(qr + c * 16, qf);
      load16f(k0 + c * 16, k0f);
      load16f(k1 + c * 16, k1f);
      #pragma unroll
      for (int j = 0; j < 16; ++j) { a0 += qf[j] * k0f[j]; a1 += qf[j] * k1f[j]; }
    }
    float s0 = a0 * 0.125f, s1 = a1 * 0.125f;
    float mm = fmaxf(s0, s1);
    float e0 = expf(s0 - mm), e1 = expf(s1 - mm);
    float inv = 1.0f / (e0 + e1 + 1e-9f);
    wgt[p][hh] = make_float2(e0 * inv, e1 * inv);
  }
  __syncthreads();

  int wave = tid >> 6, lane = tid & 63;
  int wr = wave >> 1, wc = wave & 1;
  f32x4 acc[4][4];
  #pragma unroll
  for (int m = 0; m < 4; ++m)
    #pragma unroll
    for (int n = 0; n < 4; ++n) acc[m][n] = (f32x4){0.f, 0.f, 0.f, 0.f};

  uint4 ra0[2], ra1[2], rb[2];
  auto loadS = [&](int kt) {
    #pragma unroll
    for (int j = 0; j < 2; ++j) {
      int s = wave * 128 + j * 64 + lane;
      int r = s >> 2;
      int g = (s & 3) ^ ((r >> 1) & 3);
      int gp = row0 + r; if (gp >= P) gp = P - 1;
      const ushort* vb = kv1 + ((long)(bz * C2 + 2 * gp)) * 2048 + 1024 + kt * 32 + g * 8;
      ra0[j] = *(const uint4*)vb;
      ra1[j] = *(const uint4*)(vb + 2048);
      rb[j] = *(const uint4*)(wto + (long)(col0 + r) * DIMC + kt * 32 + g * 8);
    }
  };
  auto writeS = [&](int kt, int buf) {
    #pragma unroll
    for (int j = 0; j < 2; ++j) {
      int s = wave * 128 + j * 64 + lane;
      int r = s >> 2;
      int g = (s & 3) ^ ((r >> 1) & 3);
      float2 wp = wgt[r][(kt * 32 + g * 8) >> 6];
      uint32_t ow[4];
      const uint32_t* pa = (const uint32_t*)&ra0[j];
      const uint32_t* pb = (const uint32_t*)&ra1[j];
      #pragma unroll
      for (int i = 0; i < 4; ++i) {
        float x0 = b2f((ushort)(pa[i] & 0xffff)), x1 = b2f((ushort)(pa[i] >> 16));
        float y0 = b2f((ushort)(pb[i] & 0xffff)), y1 = b2f((ushort)(pb[i] >> 16));
        ow[i] = (uint32_t)f2b(wp.x * x0 + wp.y * y0)
              | ((uint32_t)f2b(wp.x * x1 + wp.y * y1) << 16);
      }
      *(uint4*)(lA[buf] + s * 8) = *(const uint4*)ow;
      *(uint4*)(lB[buf] + s * 8) = rb[j];
    }
  };
  loadS(0); writeS(0, 0); loadS(1);
  asm volatile("s_waitcnt lgkmcnt(0)" ::: "memory");
  __builtin_amdgcn_s_barrier();

  int rr = lane & 15, g4 = lane >> 4;
  for (int kt = 0; kt < 32; ++kt) {
    if (kt + 1 < 32) writeS(kt + 1, (kt + 1) & 1);
    if (kt + 2 < 32) loadS(kt + 2);
    bf16x8 af[4], bfr[4];
    #pragma unroll
    for (int m = 0; m < 4; ++m) {
      int r = wr * 64 + m * 16 + rr;
      int slot = g4 ^ ((r >> 1) & 3);
      af[m] = *reinterpret_cast<const bf16x8*>(&lA[kt & 1][r * 32 + slot * 8]);
    }
    #pragma unroll
    for (int n = 0; n < 4; ++n) {
      int r = wc * 64 + n * 16 + rr;
      int slot = g4 ^ ((r >> 1) & 3);
      bfr[n] = *reinterpret_cast<const bf16x8*>(&lB[kt & 1][r * 32 + slot * 8]);
    }
    __builtin_amdgcn_s_setprio(1);
    #pragma unroll
    for (int m = 0; m < 4; ++m)
      #pragma unroll
      for (int n = 0; n < 4; ++n)
        acc[m][n] = __builtin_amdgcn_mfma_f32_16x16x32_bf16(af[m], bfr[n], acc[m][n], 0, 0, 0);
    __builtin_amdgcn_s_setprio(0);
    asm volatile("s_waitcnt lgkmcnt(0)" ::: "memory");
    if (kt < 31) __builtin_amdgcn_s_barrier();
  }

  int rq = lane >> 4;
  #pragma unroll
  for (int n = 0; n < 4; ++n) {
    int col = col0 + wc * 64 + n * 16 + rr;
    float bv = boy[col];
    #pragma unroll
    for (int m = 0; m < 4; ++m) {
      int gr0 = row0 + wr * 64 + m * 16 + rq * 4;
      #pragma unroll
      for (int r = 0; r < 4; ++r) {
        int gr = gr0 + r;
        if (gr < P)
          h[((long)(bz * H_NODES + offP + gr) << 10) + col] = f2b(acc[m][n][r] + bv);
      }
    }
  }
}

// ---------------- stage-2 gather attention: one wave per (b,n), all heads
__global__ void __launch_bounds__(256) attn_x2_k(const ushort* __restrict__ Q,
    const ushort* __restrict__ KV, ushort* __restrict__ outp) {
  int wave = threadIdx.x >> 6, lane = threadIdx.x & 63;
  long w = (long)blockIdx.x * 4 + wave;
  int n = (int)(w & 4095);
  int b = (int)(w >> 12);
  const ushort* KVb = KV + (long)b * H_NODES * 2048;
  float qf[16];
  load16f(Q + (((long)b * NN + n) << 10) + lane * 16, qf);
  int nb[13];
  nb[0] = n;
  #pragma unroll
  for (int l = 0; l < 12; ++l) nb[1 + l] = (8192 - (8192 >> l)) + ((n >> l) ^ 1);
  float s[13];
  #pragma unroll
  for (int i = 0; i < 13; ++i) {
    float kf[16];
    load16f(KVb + (long)nb[i] * 2048 + lane * 16, kf);
    float d = 0.f;
    #pragma unroll
    for (int j = 0; j < 16; ++j) d += qf[j] * kf[j];
    d += __shfl_xor(d, 1);
    d += __shfl_xor(d, 2);
    s[i] = d * 0.125f;
  }
  #pragma unroll
  for (int l = 0; l < 12; ++l)
    if (((n >> l) & 1) == 0) s[1 + l] = -__builtin_inff();
  float mm = s[0];
  #pragma unroll
  for (int i = 1; i < 13; ++i) mm = fmaxf(mm, s[i]);
  float e[13], sum = 0.f;
  #pragma unroll
  for (int i = 0; i < 13; ++i) { e[i] = expf(s[i] - mm); sum += e[i]; }
  float inv = 1.0f / sum;
  float ov[16];
  #pragma unroll
  for (int j = 0; j < 16; ++j) ov[j] = 0.f;
  #pragma unroll
  for (int i = 0; i < 13; ++i) {
    float wgt = e[i] * inv;
    float vf[16];
    load16f(KVb + (long)nb[i] * 2048 + 1024 + lane * 16, vf);
    #pragma unroll
    for (int j = 0; j < 16; ++j) ov[j] += wgt * vf[j];
  }
  store16b(outp + (((long)b * NN + n) << 10) + lane * 16, ov);
}

extern "C" void kernel_launch(void* const* d_in, const int* in_sizes, int n_in,
                              void* d_out, int out_size, void* d_ws, size_t ws_size,
                              hipStream_t stream) {
  const float* x    = (const float*)d_in[0];
  const float* Wq_y = (const float*)d_in[1];
  const float* Wk_y = (const float*)d_in[2];
  const float* Wv_y = (const float*)d_in[3];
  const float* Wo_y = (const float*)d_in[4];
  const float* bo_y = (const float*)d_in[5];
  const float* Wq_x = (const float*)d_in[6];
  const float* Wk_x = (const float*)d_in[7];
  const float* Wv_x = (const float*)d_in[8];
  const float* Wo_x = (const float*)d_in[9];
  const float* bo_x = (const float*)d_in[10];

  ushort* wt  = (ushort*)d_ws;                              // 8 x 1M bf16 weights^T
  ushort* h   = wt + (size_t)8 * 1024 * 1024;               // [B][8191][1024]
  ushort* reg = h + (size_t)2 * H_NODES * DIMC;
  // stage-1 view
  ushort* qb  = reg;                                        // [B][2048][1024] max
  ushort* kv1 = qb + (size_t)2 * 2048 * DIMC;               // [B][4096][2048] max
  // stage-2 view (stage-1 dead by then)
  ushort* Qx   = reg;                                       // [B][4096][1024]
  ushort* KVa  = Qx + (size_t)2 * 4096 * DIMC;              // [B][8191][2048]
  ushort* aout = KVa + (size_t)2 * H_NODES * 2048;          // [B][4096][1024]

  size_t need = ((size_t)8 * 1024 * 1024 + (size_t)2 * H_NODES * DIMC +
                 (size_t)2 * 4096 * DIMC + (size_t)2 * H_NODES * 2048 +
                 (size_t)2 * 4096 * DIMC) * 2;
  if (ws_size < need) return;

  WPtrs wp;
  wp.w[0] = Wq_y; wp.w[1] = Wk_y; wp.w[2] = Wv_y; wp.w[3] = Wo_y;
  wp.w[4] = Wq_x; wp.w[5] = Wk_x; wp.w[6] = Wv_x; wp.w[7] = Wo_x;
  transpose_w_k<<<dim3(32, 32, 8), dim3(32, 8), 0, stream>>>(wp, wt);
  cvt_x_k<<<8192, 256, 0, stream>>>(x, h);

  auto mk128 = [](const ushort* A, long sAb, const ushort* Bt, const float* bias,
                  void* C, long sCb, int ldc, int M, int outMode, int tY) {
    GemmDesc d; d.A = A; d.sAb = sAb; d.Bt = Bt; d.bias = bias; d.C = C; d.sCb = sCb;
    d.ldc = ldc; d.M = M; d.outMode = outMode; d.tX = (M + 127) / 128; d.tY = tY;
    return d;
  };

  for (int l = 0; l < 12; ++l) {
    int P = NN >> (l + 1);
    int offL = 8192 - (8192 >> l);
    int offP = 8192 - (8192 >> (l + 1));
    int qrt = (P + 127) >> 7;
    // avg+Q GEMM: A = children rows (offL), M = P
    GemmDesc dq = mk128(h + (long)offL * DIMC, (long)H_NODES * DIMC, wt, nullptr,
                        qb, (long)P * DIMC, DIMC, P, 0, 8);
    // KV GEMM: A = children rows, M = 2P
    GemmDesc dkv = mk128(h + (long)offL * DIMC, (long)H_NODES * DIMC,
                         wt + (size_t)1 * 1024 * 1024, nullptr,
                         kv1, (long)2 * P * 2048, 2048, 2 * P, 0, 16);
    int t0 = dq.tX * dq.tY * 2, t1 = dkv.tX * dkv.tY * 2;
    qkv_level_k<<<t0 + t1, 256, 0, stream>>>(dq, dkv, t0);
    mo_level_k<<<qrt * 8 * 2, 256, 0, stream>>>(
        qb, kv1, wt + (size_t)3 * 1024 * 1024, bo_y, h, P, offP, qrt);
  }

  // stage 2
  GemmDesc dqx = mk128(h, (long)H_NODES * DIMC, wt + (size_t)4 * 1024 * 1024, nullptr,
                       Qx, (long)4096 * DIMC, DIMC, 4096, 0, 8);
  GemmDesc dkva = mk128(h, (long)H_NODES * DIMC, wt + (size_t)5 * 1024 * 1024, nullptr,
                        KVa, (long)H_NODES * 2048, 2048, H_NODES, 0, 16);
  int t0 = dqx.tX * dqx.tY * 2, t1 = dkva.tX * dkva.tY * 2;
  gemm_multi<<<t0 + t1, 256, 0, stream>>>(dqx, dkva, t0);
  attn_x2_k<<<2048, 256, 0, stream>>>(Qx, KVa, aout);
  GemmDesc dox = mk128(aout, (long)4096 * DIMC, wt + (size_t)7 * 1024 * 1024, bo_x,
                       d_out, (long)4096 * DIMC, DIMC, 4096, 2, 8);
  gemm_multi<<<dox.tX * dox.tY * 2, 256, 0, stream>>>(dox, dox, dox.tX * dox.tY * 2);
}

// Round 7
// 1041.086 us; speedup vs baseline: 5.6048x; 1.2734x over previous
//
#include <hip/hip_runtime.h>
#include <stdint.h>

#define H_NODES 8191
#define NN 4096
#define DIMC 1024

typedef __bf16 bf16x8 __attribute__((ext_vector_type(8)));
typedef float f32x4 __attribute__((ext_vector_type(4)));

__device__ __forceinline__ float b2f(ushort u) {
  union { uint32_t i; float f; } x; x.i = ((uint32_t)u) << 16; return x.f;
}
__device__ __forceinline__ ushort f2b(float f) {
  union { float f; uint32_t i; } x; x.f = f;
  uint32_t r = x.i + 0x7FFFu + ((x.i >> 16) & 1u);
  return (ushort)(r >> 16);
}
__device__ __forceinline__ void load16f(const ushort* p, float* f) {
  const uint32_t* w = (const uint32_t*)p;
  #pragma unroll
  for (int i = 0; i < 8; ++i) {
    uint32_t v = w[i];
    f[2 * i]     = b2f((ushort)(v & 0xffff));
    f[2 * i + 1] = b2f((ushort)(v >> 16));
  }
}
__device__ __forceinline__ void store16b(ushort* p, const float* f) {
  uint32_t w[8];
  #pragma unroll
  for (int i = 0; i < 8; ++i)
    w[i] = (uint32_t)f2b(f[2 * i]) | ((uint32_t)f2b(f[2 * i + 1]) << 16);
  *(uint4*)p = *(const uint4*)&w[0];
  *(uint4*)(p + 8) = *(const uint4*)&w[4];
}

// ---------------- weight transpose + fp32->bf16 : dst[z][n][k] = bf16(W_z[k][n])
struct WPtrs { const float* w[8]; };

__global__ void __launch_bounds__(256) transpose_w_k(WPtrs wp, ushort* __restrict__ dst) {
  __shared__ float t[32][33];
  const float* src = wp.w[blockIdx.z];
  int c0 = blockIdx.x * 32, r0 = blockIdx.y * 32;
  int tx = threadIdx.x, ty = threadIdx.y;
  #pragma unroll
  for (int i = ty; i < 32; i += 8)
    t[i][tx] = src[(long)(r0 + i) * DIMC + c0 + tx];
  __syncthreads();
  ushort* d = dst + (long)blockIdx.z * DIMC * DIMC;
  #pragma unroll
  for (int i = ty; i < 32; i += 8)
    d[(long)(c0 + i) * DIMC + r0 + tx] = f2b(t[tx][i]);
}

// ---------------- x fp32 -> h leaf rows (bf16)
__global__ void __launch_bounds__(256) cvt_x_k(const float* __restrict__ x, ushort* __restrict__ h) {
  long t = (long)blockIdx.x * 256 + threadIdx.x;
  long i = t << 2;
  if (i >= (long)2 * NN * DIMC) return;
  long row = i >> 10;
  int col = (int)(i & 1023);
  long b = row >> 12;
  long n = row & 4095;
  float4 v = *(const float4*)(x + i);
  ushort* d = h + ((b * H_NODES + n) << 10) + col;
  uint2 pk;
  pk.x = (uint32_t)f2b(v.x) | ((uint32_t)f2b(v.y) << 16);
  pk.y = (uint32_t)f2b(v.z) | ((uint32_t)f2b(v.w) << 16);
  *(uint2*)d = pk;
}

// ---------------- pre = 0.5*(even+odd) of current level rows (bf16 in/out)
__global__ void __launch_bounds__(256) avg_pairs_k(const ushort* __restrict__ h,
    ushort* __restrict__ pre, int P, int offL) {
  long t = (long)blockIdx.x * 256 + threadIdx.x;
  if (t >= (long)2 * P * 128) return;
  int dblk = (int)(t & 127);
  long r = t >> 7;
  int b = (r >= P) ? 1 : 0;
  int p = (int)(r - (long)b * P);
  const ushort* c = h + (((long)(b * H_NODES + offL + 2 * p)) << 10) + dblk * 8;
  const uint4 a0 = *(const uint4*)c;
  const uint4 a1 = *(const uint4*)(c + DIMC);
  const uint32_t* pa = (const uint32_t*)&a0;
  const uint32_t* pb = (const uint32_t*)&a1;
  uint32_t outw[4];
  #pragma unroll
  for (int i = 0; i < 4; ++i) {
    float x0 = b2f((ushort)(pa[i] & 0xffff)), x1 = b2f((ushort)(pa[i] >> 16));
    float y0 = b2f((ushort)(pb[i] & 0xffff)), y1 = b2f((ushort)(pb[i] >> 16));
    ushort r0 = f2b(0.5f * (x0 + y0)), r1 = f2b(0.5f * (x1 + y1));
    outw[i] = (uint32_t)r0 | ((uint32_t)r1 << 16);
  }
  *(uint4*)(pre + (((long)(b * P + p)) << 10) + dblk * 8) = *(const uint4*)outw;
}

// ---------------- GEMM descriptor
struct GemmDesc {
  const ushort* A; long sAb;
  const ushort* Bt;
  const float* bias;
  void* C; long sCb; int ldc;
  int M; int outMode;   // 0 bf16, 1 bf16+bias, 2 fp32+bias
  int tX, tY;
};

// ---------------- 128x128 pipelined GEMM tile (3-buf, gload_lds) — the ONE gemm core
__device__ __forceinline__ void stage_tile(const GemmDesc& d, const ushort* Ab,
    int row0, int col0, ushort* lA, ushort* lB, int kt, int wave, int lane) {
  #pragma unroll
  for (int j = 0; j < 2; ++j) {
    int s = wave * 128 + j * 64 + lane;
    int r = s >> 2;
    int g = (s & 3) ^ ((r >> 1) & 3);       // pre-swizzled source k-block
    int gr = row0 + r; gr = (gr < d.M) ? gr : (d.M - 1);
    const ushort* srcA = Ab + (long)gr * DIMC + kt * 32 + g * 8;
    __builtin_amdgcn_global_load_lds(
        (const __attribute__((address_space(1))) void*)(uintptr_t)srcA,
        (__attribute__((address_space(3))) void*)(uint32_t)(uintptr_t)(lA + (wave * 128 + j * 64) * 8),
        16, 0, 0);
    const ushort* srcB = d.Bt + (long)(col0 + r) * DIMC + kt * 32 + g * 8;
    __builtin_amdgcn_global_load_lds(
        (const __attribute__((address_space(1))) void*)(uintptr_t)srcB,
        (__attribute__((address_space(3))) void*)(uint32_t)(uintptr_t)(lB + (wave * 128 + j * 64) * 8),
        16, 0, 0);
  }
}

__device__ __forceinline__ void gemm_tile(const GemmDesc& d, int bz, int row0, int col0,
    ushort (*lA)[4096], ushort (*lB)[4096], int tid) {
  const ushort* Ab = d.A + (long)bz * d.sAb;
  int wave = tid >> 6, lane = tid & 63;
  int wr = wave >> 1, wc = wave & 1;

  f32x4 acc[4][4];
  #pragma unroll
  for (int m = 0; m < 4; ++m)
    #pragma unroll
    for (int n = 0; n < 4; ++n) acc[m][n] = (f32x4){0.f, 0.f, 0.f, 0.f};

  stage_tile(d, Ab, row0, col0, lA[0], lB[0], 0, wave, lane);
  stage_tile(d, Ab, row0, col0, lA[1], lB[1], 1, wave, lane);
  asm volatile("s_waitcnt vmcnt(4)" ::: "memory");
  __builtin_amdgcn_s_barrier();

  int rr = lane & 15, g4 = lane >> 4;
  for (int kt = 0; kt < 32; ++kt) {
    int cur = kt % 3;
    if (kt + 2 < 32)
      stage_tile(d, Ab, row0, col0, lA[(kt + 2) % 3], lB[(kt + 2) % 3], kt + 2, wave, lane);
    bf16x8 af[4], bfr[4];
    #pragma unroll
    for (int m = 0; m < 4; ++m) {
      int r = wr * 64 + m * 16 + rr;
      int slot = g4 ^ ((r >> 1) & 3);
      af[m] = *reinterpret_cast<const bf16x8*>(&lA[cur][r * 32 + slot * 8]);
    }
    #pragma unroll
    for (int n = 0; n < 4; ++n) {
      int r = wc * 64 + n * 16 + rr;
      int slot = g4 ^ ((r >> 1) & 3);
      bfr[n] = *reinterpret_cast<const bf16x8*>(&lB[cur][r * 32 + slot * 8]);
    }
    __builtin_amdgcn_s_setprio(1);
    #pragma unroll
    for (int m = 0; m < 4; ++m)
      #pragma unroll
      for (int n = 0; n < 4; ++n)
        acc[m][n] = __builtin_amdgcn_mfma_f32_16x16x32_bf16(af[m], bfr[n], acc[m][n], 0, 0, 0);
    __builtin_amdgcn_s_setprio(0);
    if (kt < 30) { asm volatile("s_waitcnt vmcnt(4)" ::: "memory"); }
    else         { asm volatile("s_waitcnt vmcnt(0)" ::: "memory"); }
    if (kt < 31) __builtin_amdgcn_s_barrier();
  }

  int rq = lane >> 4;
  #pragma unroll
  for (int n = 0; n < 4; ++n) {
    int col = col0 + wc * 64 + n * 16 + rr;
    float bv = d.bias ? d.bias[col] : 0.0f;
    #pragma unroll
    for (int m = 0; m < 4; ++m) {
      int gr0 = row0 + wr * 64 + m * 16 + rq * 4;
      #pragma unroll
      for (int r = 0; r < 4; ++r) {
        int gr = gr0 + r;
        if (gr < d.M) {
          float vv = acc[m][n][r] + bv;
          long o = (long)bz * d.sCb + (long)gr * d.ldc + col;
          if (d.outMode == 2) ((float*)d.C)[o] = vv;
          else ((ushort*)d.C)[o] = f2b(vv);
        }
      }
    }
  }
}

// ---------------- scheduled GEMM launch: real tiles (r0,r1) + attached stage-2 windows
struct SchedArgs {
  GemmDesc r0, r1, q, kv;
  int n0, n1;           // real tile counts
  int qOff, qCnt;       // attach window into stage-2 Q tile list (standard order)
  int kvOff;            // attach window into stage-2 KV tile list (tx-major order)
};

__global__ void __launch_bounds__(256) gemm_sched_k(SchedArgs s) {
  __shared__ __align__(16) ushort lA[3][4096];
  __shared__ __align__(16) ushort lB[3][4096];
  int t = blockIdx.x;
  const GemmDesc* d;
  int idx, ord = 0;
  if (t < s.n0) { d = &s.r0; idx = t; }
  else if (t < s.n0 + s.n1) { d = &s.r1; idx = t - s.n0; }
  else if (t < s.n0 + s.n1 + s.qCnt) { d = &s.q; idx = s.qOff + (t - s.n0 - s.n1); }
  else { d = &s.kv; idx = s.kvOff + (t - s.n0 - s.n1 - s.qCnt); ord = 1; }
  int bz, tx, ty;
  if (ord) {                       // tx-major: availability-monotone enumeration
    tx = idx >> 5; int r = idx & 31; ty = r >> 1; bz = r & 1;
  } else {
    int per = d->tX * d->tY;
    bz = idx / per; int rem = idx - bz * per;
    ty = rem / d->tX; tx = rem - ty * d->tX;
  }
  gemm_tile(*d, bz, tx * 128, ty * 128, lA, lB, threadIdx.x);
}

// ---------------- stage-1 merge: one wave per (b,p), all 16 heads, 16 elems/lane
__global__ void __launch_bounds__(256) merge_y2_k(const ushort* __restrict__ q,
    const ushort* __restrict__ kv, ushort* __restrict__ outp, int P) {
  int wave = threadIdx.x >> 6, lane = threadIdx.x & 63;
  long w = (long)blockIdx.x * 4 + wave;
  if (w >= (long)2 * P) return;
  int b = (w >= P) ? 1 : 0;
  int p = (int)(w - (long)b * P);
  const ushort* qp = q + (((long)(b * P + p)) << 10) + lane * 16;
  const ushort* kvb = kv + ((long)(b * 2 * P + 2 * p)) * 2048;
  float qf[16], k0f[16], k1f[16];
  load16f(qp, qf);
  load16f(kvb + lane * 16, k0f);
  load16f(kvb + 2048 + lane * 16, k1f);
  float d0 = 0.f, d1 = 0.f;
  #pragma unroll
  for (int j = 0; j < 16; ++j) { d0 += qf[j] * k0f[j]; d1 += qf[j] * k1f[j]; }
  d0 += __shfl_xor(d0, 1); d0 += __shfl_xor(d0, 2);
  d1 += __shfl_xor(d1, 1); d1 += __shfl_xor(d1, 2);
  float s0 = d0 * 0.125f, s1 = d1 * 0.125f;
  float mm = fmaxf(s0, s1);
  float e0 = expf(s0 - mm), e1 = expf(s1 - mm);
  float inv = 1.0f / (e0 + e1 + 1e-9f);
  float w0 = e0 * inv, w1 = e1 * inv;
  float v0f[16], v1f[16], ov[16];
  load16f(kvb + 1024 + lane * 16, v0f);
  load16f(kvb + 2048 + 1024 + lane * 16, v1f);
  #pragma unroll
  for (int j = 0; j < 16; ++j) ov[j] = w0 * v0f[j] + w1 * v1f[j];
  store16b(outp + (((long)(b * P + p)) << 10) + lane * 16, ov);
}

// ---------------- stage-2 gather attention: one wave per (b,n), all heads
__global__ void __launch_bounds__(256) attn_x2_k(const ushort* __restrict__ Q,
    const ushort* __restrict__ KV, ushort* __restrict__ outp) {
  int wave = threadIdx.x >> 6, lane = threadIdx.x & 63;
  long w = (long)blockIdx.x * 4 + wave;
  int n = (int)(w & 4095);
  int b = (int)(w >> 12);
  const ushort* KVb = KV + (long)b * H_NODES * 2048;
  float qf[16];
  load16f(Q + (((long)b * NN + n) << 10) + lane * 16, qf);
  int nb[13];
  nb[0] = n;
  #pragma unroll
  for (int l = 0; l < 12; ++l) nb[1 + l] = (8192 - (8192 >> l)) + ((n >> l) ^ 1);
  float s[13];
  #pragma unroll
  for (int i = 0; i < 13; ++i) {
    float kf[16];
    load16f(KVb + (long)nb[i] * 2048 + lane * 16, kf);
    float d = 0.f;
    #pragma unroll
    for (int j = 0; j < 16; ++j) d += qf[j] * kf[j];
    d += __shfl_xor(d, 1);
    d += __shfl_xor(d, 2);
    s[i] = d * 0.125f;
  }
  #pragma unroll
  for (int l = 0; l < 12; ++l)
    if (((n >> l) & 1) == 0) s[1 + l] = -__builtin_inff();
  float mm = s[0];
  #pragma unroll
  for (int i = 1; i < 13; ++i) mm = fmaxf(mm, s[i]);
  float e[13], sum = 0.f;
  #pragma unroll
  for (int i = 0; i < 13; ++i) { e[i] = expf(s[i] - mm); sum += e[i]; }
  float inv = 1.0f / sum;
  float ov[16];
  #pragma unroll
  for (int j = 0; j < 16; ++j) ov[j] = 0.f;
  #pragma unroll
  for (int i = 0; i < 13; ++i) {
    float wgt = e[i] * inv;
    float vf[16];
    load16f(KVb + (long)nb[i] * 2048 + 1024 + lane * 16, vf);
    #pragma unroll
    for (int j = 0; j < 16; ++j) ov[j] += wgt * vf[j];
  }
  store16b(outp + (((long)b * NN + n) << 10) + lane * 16, ov);
}

extern "C" void kernel_launch(void* const* d_in, const int* in_sizes, int n_in,
                              void* d_out, int out_size, void* d_ws, size_t ws_size,
                              hipStream_t stream) {
  const float* x    = (const float*)d_in[0];
  const float* Wq_y = (const float*)d_in[1];
  const float* Wk_y = (const float*)d_in[2];
  const float* Wv_y = (const float*)d_in[3];
  const float* Wo_y = (const float*)d_in[4];
  const float* bo_y = (const float*)d_in[5];
  const float* Wq_x = (const float*)d_in[6];
  const float* Wk_x = (const float*)d_in[7];
  const float* Wv_x = (const float*)d_in[8];
  const float* Wo_x = (const float*)d_in[9];
  const float* bo_x = (const float*)d_in[10];

  ushort* wt  = (ushort*)d_ws;                              // 8 x 1M bf16 weights^T
  ushort* h   = wt + (size_t)8 * 1024 * 1024;               // [B][8191][1024]
  ushort* reg = h + (size_t)2 * H_NODES * DIMC;
  // stage-2 layout (attached writes begin at level 3)
  ushort* Qx   = reg;                                       // [B][4096][1024]
  ushort* KVa  = Qx + (size_t)2 * 4096 * DIMC;              // [B][8191][2048]
  ushort* aout = KVa + (size_t)2 * H_NODES * 2048;          // [B][4096][1024]
  // stage-1 big-level scratch (levels 0-2; aliases Qx/KVa, dead before attach starts)
  ushort* preB = reg;
  ushort* qbB  = preB + (size_t)2 * 2048 * DIMC;
  ushort* kv1B = qbB + (size_t)2 * 2048 * DIMC;
  ushort* mrgB = kv1B + (size_t)2 * 4096 * 2048;
  // stage-1 small-level scratch (levels 3-11; inside aout, which attn writes last)
  ushort* preS = aout;
  ushort* qbS  = preS + (size_t)2 * 256 * DIMC;
  ushort* kv1S = qbS + (size_t)2 * 256 * DIMC;
  ushort* mrgS = kv1S + (size_t)2 * 512 * 2048;

  size_t need = ((size_t)8 * 1024 * 1024 + (size_t)2 * H_NODES * DIMC +
                 (size_t)2 * 4096 * DIMC + (size_t)2 * H_NODES * 2048 +
                 (size_t)2 * 4096 * DIMC) * 2;
  if (ws_size < need) return;

  WPtrs wp;
  wp.w[0] = Wq_y; wp.w[1] = Wk_y; wp.w[2] = Wv_y; wp.w[3] = Wo_y;
  wp.w[4] = Wq_x; wp.w[5] = Wk_x; wp.w[6] = Wv_x; wp.w[7] = Wo_x;
  transpose_w_k<<<dim3(32, 32, 8), dim3(32, 8), 0, stream>>>(wp, wt);
  cvt_x_k<<<8192, 256, 0, stream>>>(x, h);

  auto mk128 = [](const ushort* A, long sAb, const ushort* Bt, const float* bias,
                  void* C, long sCb, int ldc, int M, int outMode, int tY) {
    GemmDesc d; d.A = A; d.sAb = sAb; d.Bt = Bt; d.bias = bias; d.C = C; d.sCb = sCb;
    d.ldc = ldc; d.M = M; d.outMode = outMode; d.tX = (M + 127) / 128; d.tY = tY;
    return d;
  };

  // stage-2 attach pools
  GemmDesc dQat = mk128(h, (long)H_NODES * DIMC, wt + (size_t)4 * 1024 * 1024, nullptr,
                        Qx, (long)4096 * DIMC, DIMC, 4096, 0, 8);          // 32x8x2 = 512 tiles
  GemmDesc dKat = mk128(h, (long)H_NODES * DIMC, wt + (size_t)5 * 1024 * 1024, nullptr,
                        KVa, (long)H_NODES * 2048, 2048, H_NODES, 0, 16);  // 64x16x2 = 2048 tiles
  const int QTOT = 512, KVTOT = 2048, RATION = 160;
  int qCur = 0, kvCur = 0;

  auto sched = [&](GemmDesc r0, int n0, GemmDesc r1, int n1, int l) {
    int aq = 0, akv = 0;
    if (l >= 3) {
      int cap = 512 - (n0 + n1);
      if (cap > RATION) cap = RATION;
      if (cap < 0) cap = 0;
      // rows available at this dispatch: leaves + parents of levels < l
      int kvLimit = ((8192 - (8192 >> (l + 1))) >> 7) * 32;
      if (kvLimit > KVTOT) kvLimit = KVTOT;
      aq = QTOT - qCur; if (aq > cap) aq = cap;
      akv = kvLimit - kvCur; if (akv > cap - aq) akv = cap - aq; if (akv < 0) akv = 0;
    }
    SchedArgs s; s.r0 = r0; s.r1 = r1; s.q = dQat; s.kv = dKat;
    s.n0 = n0; s.n1 = n1; s.qOff = qCur; s.qCnt = aq; s.kvOff = kvCur;
    gemm_sched_k<<<n0 + n1 + aq + akv, 256, 0, stream>>>(s);
    qCur += aq; kvCur += akv;
  };

  for (int l = 0; l < 12; ++l) {
    int P = NN >> (l + 1);
    int offL = 8192 - (8192 >> l);
    int offP = 8192 - (8192 >> (l + 1));
    bool small = (l >= 3);
    ushort* pre = small ? preS : preB;
    ushort* qb  = small ? qbS  : qbB;
    ushort* kv1 = small ? kv1S : kv1B;
    ushort* mrg = small ? mrgS : mrgB;
    avg_pairs_k<<<(2 * P * 128 + 255) / 256, 256, 0, stream>>>(h, pre, P, offL);
    GemmDesc dq  = mk128(pre, (long)P * DIMC, wt, nullptr,
                         qb, (long)P * DIMC, DIMC, P, 0, 8);
    GemmDesc dkv = mk128(h + (long)offL * DIMC, (long)H_NODES * DIMC,
                         wt + (size_t)1 * 1024 * 1024, nullptr,
                         kv1, (long)2 * P * 2048, 2048, 2 * P, 0, 16);
    sched(dq, dq.tX * dq.tY * 2, dkv, dkv.tX * dkv.tY * 2, l);
    merge_y2_k<<<(2 * P + 3) / 4, 256, 0, stream>>>(qb, kv1, mrg, P);
    GemmDesc dgo = mk128(mrg, (long)P * DIMC, wt + (size_t)3 * 1024 * 1024, bo_y,
                         h + (long)offP * DIMC, (long)H_NODES * DIMC, DIMC, P, 1, 8);
    sched(dgo, dgo.tX * dgo.tY * 2, dgo, 0, l);
  }

  // stage-2 leftovers (Q remainder + KV tiles not yet attachable, e.g. root tile)
  {
    SchedArgs s; s.r0 = dQat; s.n0 = 0; s.r1 = dQat; s.n1 = 0; s.q = dQat; s.kv = dKat;
    s.qOff = qCur; s.qCnt = QTOT - qCur; s.kvOff = kvCur;
    int grid = s.qCnt + (KVTOT - kvCur);
    if (grid > 0) gemm_sched_k<<<grid, 256, 0, stream>>>(s);
  }
  attn_x2_k<<<2048, 256, 0, stream>>>(Qx, KVa, aout);
  {
    GemmDesc dox = mk128(aout, (long)4096 * DIMC, wt + (size_t)7 * 1024 * 1024, bo_x,
                         d_out, (long)4096 * DIMC, DIMC, 4096, 2, 8);
    SchedArgs s; s.r0 = dox; s.n0 = dox.tX * dox.tY * 2; s.r1 = dox; s.n1 = 0;
    s.q = dQat; s.kv = dKat; s.qOff = 0; s.qCnt = 0; s.kvOff = 0;
    gemm_sched_k<<<s.n0, 256, 0, stream>>>(s);
  }
}

// Round 8
// 661.271 us; speedup vs baseline: 8.8240x; 1.5744x over previous
//
#include <hip/hip_runtime.h>
#include <stdint.h>

#define H_NODES 8191
#define NN 4096
#define DIMC 1024

typedef __bf16 bf16x8 __attribute__((ext_vector_type(8)));
typedef float f32x4 __attribute__((ext_vector_type(4)));

__device__ __forceinline__ float b2f(ushort u) {
  union { uint32_t i; float f; } x; x.i = ((uint32_t)u) << 16; return x.f;
}
__device__ __forceinline__ ushort f2b(float f) {
  union { float f; uint32_t i; } x; x.f = f;
  uint32_t r = x.i + 0x7FFFu + ((x.i >> 16) & 1u);
  return (ushort)(r >> 16);
}
__device__ __forceinline__ void load16f(const ushort* p, float* f) {
  const uint32_t* w = (const uint32_t*)p;
  #pragma unroll
  for (int i = 0; i < 8; ++i) {
    uint32_t v = w[i];
    f[2 * i]     = b2f((ushort)(v & 0xffff));
    f[2 * i + 1] = b2f((ushort)(v >> 16));
  }
}
__device__ __forceinline__ void store16b(ushort* p, const float* f) {
  uint32_t w[8];
  #pragma unroll
  for (int i = 0; i < 8; ++i)
    w[i] = (uint32_t)f2b(f[2 * i]) | ((uint32_t)f2b(f[2 * i + 1]) << 16);
  *(uint4*)p = *(const uint4*)&w[0];
  *(uint4*)(p + 8) = *(const uint4*)&w[4];
}

// ---------------- weight transpose + fp32->bf16 : dst[z][n][k] = bf16(W_z[k][n])
struct WPtrs { const float* w[8]; };

__global__ void __launch_bounds__(256) transpose_w_k(WPtrs wp, ushort* __restrict__ dst) {
  __shared__ float t[32][33];
  const float* src = wp.w[blockIdx.z];
  int c0 = blockIdx.x * 32, r0 = blockIdx.y * 32;
  int tx = threadIdx.x, ty = threadIdx.y;
  #pragma unroll
  for (int i = ty; i < 32; i += 8)
    t[i][tx] = src[(long)(r0 + i) * DIMC + c0 + tx];
  __syncthreads();
  ushort* d = dst + (long)blockIdx.z * DIMC * DIMC;
  #pragma unroll
  for (int i = ty; i < 32; i += 8)
    d[(long)(c0 + i) * DIMC + r0 + tx] = f2b(t[tx][i]);
}

// ---------------- x fp32 -> h leaf rows (bf16)
__global__ void __launch_bounds__(256) cvt_x_k(const float* __restrict__ x, ushort* __restrict__ h) {
  long t = (long)blockIdx.x * 256 + threadIdx.x;
  long i = t << 2;
  if (i >= (long)2 * NN * DIMC) return;
  long row = i >> 10;
  int col = (int)(i & 1023);
  long b = row >> 12;
  long n = row & 4095;
  float4 v = *(const float4*)(x + i);
  ushort* d = h + ((b * H_NODES + n) << 10) + col;
  uint2 pk;
  pk.x = (uint32_t)f2b(v.x) | ((uint32_t)f2b(v.y) << 16);
  pk.y = (uint32_t)f2b(v.z) | ((uint32_t)f2b(v.w) << 16);
  *(uint2*)d = pk;
}

// ---------------- pre = 0.5*(even+odd) — used ONCE for level 0
__global__ void __launch_bounds__(256) avg_pairs_k(const ushort* __restrict__ h,
    ushort* __restrict__ pre, int P, int offL) {
  long t = (long)blockIdx.x * 256 + threadIdx.x;
  if (t >= (long)2 * P * 128) return;
  int dblk = (int)(t & 127);
  long r = t >> 7;
  int b = (r >= P) ? 1 : 0;
  int p = (int)(r - (long)b * P);
  const ushort* c = h + (((long)(b * H_NODES + offL + 2 * p)) << 10) + dblk * 8;
  const uint4 a0 = *(const uint4*)c;
  const uint4 a1 = *(const uint4*)(c + DIMC);
  const uint32_t* pa = (const uint32_t*)&a0;
  const uint32_t* pb = (const uint32_t*)&a1;
  uint32_t outw[4];
  #pragma unroll
  for (int i = 0; i < 4; ++i) {
    float x0 = b2f((ushort)(pa[i] & 0xffff)), x1 = b2f((ushort)(pa[i] >> 16));
    float y0 = b2f((ushort)(pb[i] & 0xffff)), y1 = b2f((ushort)(pb[i] >> 16));
    ushort r0 = f2b(0.5f * (x0 + y0)), r1 = f2b(0.5f * (x1 + y1));
    outw[i] = (uint32_t)r0 | ((uint32_t)r1 << 16);
  }
  *(uint4*)(pre + (((long)(b * P + p)) << 10) + dblk * 8) = *(const uint4*)outw;
}

// ---------------- GEMM descriptor
struct GemmDesc {
  const ushort* A; long sAb;
  const ushort* Bt;
  const float* bias;
  void* C; long sCb; int ldc;
  int M; int outMode;     // 0 bf16, 1 bf16+bias, 2 fp32+bias
  int tX, tY;
  ushort* preC;           // optional: next-level pre output (avg of row pairs)
  long sPreB;             // batch stride of preC
};

// ---------------- 128x128 pipelined GEMM tile (3-buf, gload_lds) — the ONE gemm core
__device__ __forceinline__ void stage_tile(const GemmDesc& d, const ushort* Ab,
    int row0, int col0, ushort* lA, ushort* lB, int kt, int wave, int lane) {
  #pragma unroll
  for (int j = 0; j < 2; ++j) {
    int s = wave * 128 + j * 64 + lane;
    int r = s >> 2;
    int g = (s & 3) ^ ((r >> 1) & 3);       // pre-swizzled source k-block
    int gr = row0 + r; gr = (gr < d.M) ? gr : (d.M - 1);
    const ushort* srcA = Ab + (long)gr * DIMC + kt * 32 + g * 8;
    __builtin_amdgcn_global_load_lds(
        (const __attribute__((address_space(1))) void*)(uintptr_t)srcA,
        (__attribute__((address_space(3))) void*)(uint32_t)(uintptr_t)(lA + (wave * 128 + j * 64) * 8),
        16, 0, 0);
    const ushort* srcB = d.Bt + (long)(col0 + r) * DIMC + kt * 32 + g * 8;
    __builtin_amdgcn_global_load_lds(
        (const __attribute__((address_space(1))) void*)(uintptr_t)srcB,
        (__attribute__((address_space(3))) void*)(uint32_t)(uintptr_t)(lB + (wave * 128 + j * 64) * 8),
        16, 0, 0);
  }
}

__device__ __forceinline__ void gemm_tile(const GemmDesc& d, int bz, int row0, int col0,
    ushort (*lA)[4096], ushort (*lB)[4096], int tid) {
  const ushort* Ab = d.A + (long)bz * d.sAb;
  int wave = tid >> 6, lane = tid & 63;
  int wr = wave >> 1, wc = wave & 1;

  f32x4 acc[4][4];
  #pragma unroll
  for (int m = 0; m < 4; ++m)
    #pragma unroll
    for (int n = 0; n < 4; ++n) acc[m][n] = (f32x4){0.f, 0.f, 0.f, 0.f};

  stage_tile(d, Ab, row0, col0, lA[0], lB[0], 0, wave, lane);
  stage_tile(d, Ab, row0, col0, lA[1], lB[1], 1, wave, lane);
  asm volatile("s_waitcnt vmcnt(4)" ::: "memory");
  __builtin_amdgcn_s_barrier();

  int rr = lane & 15, g4 = lane >> 4;
  for (int kt = 0; kt < 32; ++kt) {
    int cur = kt % 3;
    if (kt + 2 < 32)
      stage_tile(d, Ab, row0, col0, lA[(kt + 2) % 3], lB[(kt + 2) % 3], kt + 2, wave, lane);
    bf16x8 af[4], bfr[4];
    #pragma unroll
    for (int m = 0; m < 4; ++m) {
      int r = wr * 64 + m * 16 + rr;
      int slot = g4 ^ ((r >> 1) & 3);
      af[m] = *reinterpret_cast<const bf16x8*>(&lA[cur][r * 32 + slot * 8]);
    }
    #pragma unroll
    for (int n = 0; n < 4; ++n) {
      int r = wc * 64 + n * 16 + rr;
      int slot = g4 ^ ((r >> 1) & 3);
      bfr[n] = *reinterpret_cast<const bf16x8*>(&lB[cur][r * 32 + slot * 8]);
    }
    __builtin_amdgcn_s_setprio(1);
    #pragma unroll
    for (int m = 0; m < 4; ++m)
      #pragma unroll
      for (int n = 0; n < 4; ++n)
        acc[m][n] = __builtin_amdgcn_mfma_f32_16x16x32_bf16(af[m], bfr[n], acc[m][n], 0, 0, 0);
    __builtin_amdgcn_s_setprio(0);
    if (kt < 30) { asm volatile("s_waitcnt vmcnt(4)" ::: "memory"); }
    else         { asm volatile("s_waitcnt vmcnt(0)" ::: "memory"); }
    if (kt < 31) __builtin_amdgcn_s_barrier();
  }

  int rq = lane >> 4;
  #pragma unroll
  for (int n = 0; n < 4; ++n) {
    int col = col0 + wc * 64 + n * 16 + rr;
    float bv = d.bias ? d.bias[col] : 0.0f;
    #pragma unroll
    for (int m = 0; m < 4; ++m) {
      int gr0 = row0 + wr * 64 + m * 16 + rq * 4;
      float vv[4];
      #pragma unroll
      for (int r = 0; r < 4; ++r) vv[r] = acc[m][n][r] + bv;
      #pragma unroll
      for (int r = 0; r < 4; ++r) {
        int gr = gr0 + r;
        if (gr < d.M) {
          long o = (long)bz * d.sCb + (long)gr * d.ldc + col;
          if (d.outMode == 2) ((float*)d.C)[o] = vv[r];
          else ((ushort*)d.C)[o] = f2b(vv[r]);
        }
      }
      if (d.preC) {   // fused next-level pre: avg of adjacent row pairs (thread-local)
        #pragma unroll
        for (int r = 0; r < 4; r += 2) {
          int gr = gr0 + r;
          if (gr + 1 < d.M)
            d.preC[(long)bz * d.sPreB + (long)(gr >> 1) * DIMC + col] =
                f2b(0.5f * (vv[r] + vv[r + 1]));
        }
      }
    }
  }
}

// ---------------- the ONE GEMM kernel: two descriptors per launch
__global__ void __launch_bounds__(256) gemm_multi(GemmDesc d0, GemmDesc d1, int t0) {
  __shared__ __align__(16) ushort lA[3][4096];
  __shared__ __align__(16) ushort lB[3][4096];
  int t = blockIdx.x;
  const GemmDesc& d = (t < t0) ? d0 : d1;
  int u = (t < t0) ? t : t - t0;
  int per = d.tX * d.tY;
  int bz = u / per;
  int rem = u - bz * per;
  int ty = rem / d.tX;
  int tx = rem - ty * d.tX;
  gemm_tile(d, bz, tx * 128, ty * 128, lA, lB, threadIdx.x);
}

// ---------------- stage-1 merge: one wave per (b,p), all 16 heads, 16 elems/lane
__global__ void __launch_bounds__(256) merge_y2_k(const ushort* __restrict__ q,
    const ushort* __restrict__ kv, ushort* __restrict__ outp, int P) {
  int wave = threadIdx.x >> 6, lane = threadIdx.x & 63;
  long w = (long)blockIdx.x * 4 + wave;
  if (w >= (long)2 * P) return;
  int b = (w >= P) ? 1 : 0;
  int p = (int)(w - (long)b * P);
  const ushort* qp = q + (((long)(b * P + p)) << 10) + lane * 16;
  const ushort* kvb = kv + ((long)(b * 2 * P + 2 * p)) * 2048;
  float qf[16], k0f[16], k1f[16];
  load16f(qp, qf);
  load16f(kvb + lane * 16, k0f);
  load16f(kvb + 2048 + lane * 16, k1f);
  float d0 = 0.f, d1 = 0.f;
  #pragma unroll
  for (int j = 0; j < 16; ++j) { d0 += qf[j] * k0f[j]; d1 += qf[j] * k1f[j]; }
  d0 += __shfl_xor(d0, 1); d0 += __shfl_xor(d0, 2);
  d1 += __shfl_xor(d1, 1); d1 += __shfl_xor(d1, 2);
  float s0 = d0 * 0.125f, s1 = d1 * 0.125f;
  float mm = fmaxf(s0, s1);
  float e0 = expf(s0 - mm), e1 = expf(s1 - mm);
  float inv = 1.0f / (e0 + e1 + 1e-9f);
  float w0 = e0 * inv, w1 = e1 * inv;
  float v0f[16], v1f[16], ov[16];
  load16f(kvb + 1024 + lane * 16, v0f);
  load16f(kvb + 2048 + 1024 + lane * 16, v1f);
  #pragma unroll
  for (int j = 0; j < 16; ++j) ov[j] = w0 * v0f[j] + w1 * v1f[j];
  store16b(outp + (((long)(b * P + p)) << 10) + lane * 16, ov);
}

// ---------------- stage-2 gather attention: one wave per (b,n), all heads
__global__ void __launch_bounds__(256) attn_x2_k(const ushort* __restrict__ Q,
    const ushort* __restrict__ KV, ushort* __restrict__ outp) {
  int wave = threadIdx.x >> 6, lane = threadIdx.x & 63;
  long w = (long)blockIdx.x * 4 + wave;
  int n = (int)(w & 4095);
  int b = (int)(w >> 12);
  const ushort* KVb = KV + (long)b * H_NODES * 2048;
  float qf[16];
  load16f(Q + (((long)b * NN + n) << 10) + lane * 16, qf);
  int nb[13];
  nb[0] = n;
  #pragma unroll
  for (int l = 0; l < 12; ++l) nb[1 + l] = (8192 - (8192 >> l)) + ((n >> l) ^ 1);
  float s[13];
  #pragma unroll
  for (int i = 0; i < 13; ++i) {
    float kf[16];
    load16f(KVb + (long)nb[i] * 2048 + lane * 16, kf);
    float d = 0.f;
    #pragma unroll
    for (int j = 0; j < 16; ++j) d += qf[j] * kf[j];
    d += __shfl_xor(d, 1);
    d += __shfl_xor(d, 2);
    s[i] = d * 0.125f;
  }
  #pragma unroll
  for (int l = 0; l < 12; ++l)
    if (((n >> l) & 1) == 0) s[1 + l] = -__builtin_inff();
  float mm = s[0];
  #pragma unroll
  for (int i = 1; i < 13; ++i) mm = fmaxf(mm, s[i]);
  float e[13], sum = 0.f;
  #pragma unroll
  for (int i = 0; i < 13; ++i) { e[i] = expf(s[i] - mm); sum += e[i]; }
  float inv = 1.0f / sum;
  float ov[16];
  #pragma unroll
  for (int j = 0; j < 16; ++j) ov[j] = 0.f;
  #pragma unroll
  for (int i = 0; i < 13; ++i) {
    float wgt = e[i] * inv;
    float vf[16];
    load16f(KVb + (long)nb[i] * 2048 + 1024 + lane * 16, vf);
    #pragma unroll
    for (int j = 0; j < 16; ++j) ov[j] += wgt * vf[j];
  }
  store16b(outp + (((long)b * NN + n) << 10) + lane * 16, ov);
}

extern "C" void kernel_launch(void* const* d_in, const int* in_sizes, int n_in,
                              void* d_out, int out_size, void* d_ws, size_t ws_size,
                              hipStream_t stream) {
  const float* x    = (const float*)d_in[0];
  const float* Wq_y = (const float*)d_in[1];
  const float* Wk_y = (const float*)d_in[2];
  const float* Wv_y = (const float*)d_in[3];
  const float* Wo_y = (const float*)d_in[4];
  const float* bo_y = (const float*)d_in[5];
  const float* Wq_x = (const float*)d_in[6];
  const float* Wk_x = (const float*)d_in[7];
  const float* Wv_x = (const float*)d_in[8];
  const float* Wo_x = (const float*)d_in[9];
  const float* bo_x = (const float*)d_in[10];

  ushort* wt  = (ushort*)d_ws;                              // 8 x 1M bf16 weights^T
  ushort* h   = wt + (size_t)8 * 1024 * 1024;               // [B][8191][1024]
  ushort* reg = h + (size_t)2 * H_NODES * DIMC;
  // stage-2 layout (attached writes begin at level-4 O launch)
  ushort* Qx   = reg;                                       // [B][4096][1024]
  ushort* KVa  = Qx + (size_t)2 * 4096 * DIMC;              // [B][8191][2048]
  ushort* aout = KVa + (size_t)2 * H_NODES * 2048;          // [B][4096][1024]
  // stage-1 big-level scratch (levels 0-2; aliases Qx/KVa, dead before attaches)
  ushort* preB = reg;                                       // [B][2048][1024]
  ushort* qbB  = preB + (size_t)2 * 2048 * DIMC;
  ushort* kv1B = qbB + (size_t)2 * 2048 * DIMC;             // [B][4096][2048]
  ushort* mrgB = kv1B + (size_t)2 * 4096 * 2048;
  // stage-1 small-level scratch (levels 3-11; inside aout, overwritten only by attn)
  ushort* preS = aout;                                      // [B][256][1024]
  ushort* qbS  = preS + (size_t)2 * 256 * DIMC;
  ushort* kv1S = qbS + (size_t)2 * 256 * DIMC;              // [B][512][2048]
  ushort* mrgS = kv1S + (size_t)2 * 512 * 2048;

  size_t need = ((size_t)8 * 1024 * 1024 + (size_t)2 * H_NODES * DIMC +
                 (size_t)2 * 4096 * DIMC + (size_t)2 * H_NODES * 2048 +
                 (size_t)2 * 4096 * DIMC) * 2;
  if (ws_size < need) return;

  WPtrs wp;
  wp.w[0] = Wq_y; wp.w[1] = Wk_y; wp.w[2] = Wv_y; wp.w[3] = Wo_y;
  wp.w[4] = Wq_x; wp.w[5] = Wk_x; wp.w[6] = Wv_x; wp.w[7] = Wo_x;
  transpose_w_k<<<dim3(32, 32, 8), dim3(32, 8), 0, stream>>>(wp, wt);
  cvt_x_k<<<8192, 256, 0, stream>>>(x, h);
  avg_pairs_k<<<(2 * 2048 * 128 + 255) / 256, 256, 0, stream>>>(h, preB, 2048, 0);

  auto mk128 = [](const ushort* A, long sAb, const ushort* Bt, const float* bias,
                  void* C, long sCb, int ldc, int M, int outMode, int tY) {
    GemmDesc d; d.A = A; d.sAb = sAb; d.Bt = Bt; d.bias = bias; d.C = C; d.sCb = sCb;
    d.ldc = ldc; d.M = M; d.outMode = outMode; d.tX = (M + 127) / 128; d.tY = tY;
    d.preC = nullptr; d.sPreB = 0;
    return d;
  };
  auto kvSub = [&](long start, int len) {
    return mk128(h + start * DIMC, (long)H_NODES * DIMC, wt + (size_t)5 * 1024 * 1024,
                 nullptr, KVa + start * 2048, (long)H_NODES * 2048, 2048, len, 0, 16);
  };

  for (int l = 0; l < 12; ++l) {
    int P = NN >> (l + 1);
    int offL = 8192 - (8192 >> l);
    int offP = 8192 - (8192 >> (l + 1));
    bool small = (l >= 3);
    ushort* pre = small ? preS : preB;
    ushort* qb  = small ? qbS  : qbB;
    ushort* kv1 = small ? kv1S : kv1B;
    ushort* mrg = small ? mrgS : mrgB;

    GemmDesc dq  = mk128(pre, (long)P * DIMC, wt, nullptr,
                         qb, (long)P * DIMC, DIMC, P, 0, 8);
    GemmDesc dkv = mk128(h + (long)offL * DIMC, (long)H_NODES * DIMC,
                         wt + (size_t)1 * 1024 * 1024, nullptr,
                         kv1, (long)2 * P * 2048, 2048, 2 * P, 0, 16);
    int t0 = dq.tX * dq.tY * 2;
    gemm_multi<<<t0 + dkv.tX * dkv.tY * 2, 256, 0, stream>>>(dq, dkv, t0);

    merge_y2_k<<<(2 * P + 3) / 4, 256, 0, stream>>>(qb, kv1, mrg, P);

    GemmDesc dgo = mk128(mrg, (long)P * DIMC, wt + (size_t)3 * 1024 * 1024, bo_y,
                         h + (long)offP * DIMC, (long)H_NODES * DIMC, DIMC, P, 1, 8);
    if (l < 11) {                       // fused pre for next level
      dgo.preC = (l >= 2) ? preS : preB;
      dgo.sPreB = (long)(P / 2) * DIMC;
    }
    // attached stage-2 sub-GEMMs (availability: KV rows < 8192 - P(l-1) after level l-1 O)
    GemmDesc att = dgo; int nAtt = 0;
    if (l == 4)      { att = kvSub(0, 2048); }
    else if (l == 5) { att = kvSub(2048, 2048); }
    else if (l == 6) { att = kvSub(4096, 2048); }
    else if (l == 7) { att = kvSub(6144, 1792); }
    else if (l == 8) { att = kvSub(7936, 240); }
    else if (l == 9) { att = mk128(h, (long)H_NODES * DIMC, wt + (size_t)4 * 1024 * 1024,
                                   nullptr, Qx, (long)4096 * DIMC, DIMC, 4096, 0, 8); }
    else if (l == 10) { att = kvSub(8176, 12); }
    else if (l == 11) { att = kvSub(8188, 2); }
    if (l >= 4) nAtt = att.tX * att.tY * 2;
    int n0 = dgo.tX * dgo.tY * 2;
    gemm_multi<<<n0 + nAtt, 256, 0, stream>>>(dgo, att, n0);
  }

  // leftover: root KV row (written by level-11 O)
  {
    GemmDesc att = kvSub(8190, 1);
    gemm_multi<<<att.tX * att.tY * 2, 256, 0, stream>>>(att, att, att.tX * att.tY * 2);
  }
  attn_x2_k<<<2048, 256, 0, stream>>>(Qx, KVa, aout);
  {
    GemmDesc dox = mk128(aout, (long)4096 * DIMC, wt + (size_t)7 * 1024 * 1024, bo_x,
                         d_out, (long)4096 * DIMC, DIMC, 4096, 2, 8);
    gemm_multi<<<dox.tX * dox.tY * 2, 256, 0, stream>>>(dox, dox, dox.tX * dox.tY * 2);
  }
}